// Round 2
// baseline (306.978 us; speedup 1.0000x reference)
//
#include <hip/hip_runtime.h>
#include <math.h>

#define N_NODES   30000
#define N_EDGE    300000
#define N_EDGE_T  330000   // + self loops
#define HEADS     8
#define HIDDEN    64
#define IN_DIM    8
#define OUT_DIM   8
#define NEG_SLOPE 0.2f

// Opaque def: value now originates from asm -> cannot be rematerialized by
// re-loading; forces it to stay VGPR-resident across the loop.
#define PIN_V(v) asm volatile("" : "+v"(v))

// ---- DPP cross-lane reductions (pure VALU; no lgkmcnt, unlike ds_swizzle) ----
#define DPP_ADDF(x, ctrl)                                                     \
    x += __int_as_float(__builtin_amdgcn_update_dpp(                          \
            0, __float_as_int(x), (ctrl), 0xF, 0xF, true))
// sum over aligned 16-lane group (all 16 lanes get the total):
#define RED16(x) do { DPP_ADDF(x, 0xB1); DPP_ADDF(x, 0x4E);                   \
                      DPP_ADDF(x, 0x141); DPP_ADDF(x, 0x140); } while (0)
// sum over aligned 8-lane group:
#define RED8(x)  do { DPP_ADDF(x, 0xB1); DPP_ADDF(x, 0x4E);                   \
                      DPP_ADDF(x, 0x141); } while (0)

// ---------------- CSR build ----------------

__global__ __launch_bounds__(256) void zero_kernel(int* __restrict__ count) {
    int i = blockIdx.x * 256 + threadIdx.x;
    if (i < N_NODES) count[i] = 0;
}

__global__ __launch_bounds__(256) void count_kernel(const int* __restrict__ ei,
                                                    int* __restrict__ count) {
    int e = blockIdx.x * 256 + threadIdx.x;
    if (e >= N_EDGE_T) return;
    int d = (e < N_EDGE) ? ei[N_EDGE + e] : (e - N_EDGE);
    atomicAdd(&count[d], 1);
}

// Single-block scan, 8 ints/thread via 2x int4: 4 rounds.
__global__ __launch_bounds__(1024) void scan_kernel(const int* __restrict__ count,
                                                    int* __restrict__ row_start,
                                                    int* __restrict__ cursor) {
    __shared__ int wsum[16];
    const int tid  = threadIdx.x;
    const int wave = tid >> 6;
    const int lane = tid & 63;
    const int4* c4 = (const int4*)count;
    const int N4 = N_NODES / 4;              // 7500 int4s exactly
    int run = 0;
    for (int r = 0; r < 4; ++r) {
        const int g  = r * 1024 + tid;       // thread-slot in round
        const int i0 = 2 * g;                // int4 idx of first half
        const int i1 = 2 * g + 1;
        int4 v0 = make_int4(0,0,0,0), v1 = make_int4(0,0,0,0);
        if (i0 < N4) v0 = c4[i0];
        if (i1 < N4) v1 = c4[i1];
        int s = v0.x + v0.y + v0.z + v0.w + v1.x + v1.y + v1.z + v1.w;
        int sc = s;
        #pragma unroll
        for (int off = 1; off < 64; off <<= 1) {
            int t = __shfl_up(sc, off, 64);
            if (lane >= off) sc += t;
        }
        if (lane == 63) wsum[wave] = sc;
        __syncthreads();
        if (tid < 16) {
            int w = wsum[tid];
            #pragma unroll
            for (int off = 1; off < 16; off <<= 1) {
                int t = __shfl_up(w, off, 64);
                if (tid >= off) w += t;
            }
            wsum[tid] = w;
        }
        __syncthreads();
        const int woff = (wave > 0) ? wsum[wave - 1] : 0;
        int e0 = run + woff + (sc - s);       // exclusive prefix of this thread's 8
        int4 ex0, ex1;
        ex0.x = e0;           ex0.y = ex0.x + v0.x;
        ex0.z = ex0.y + v0.y; ex0.w = ex0.z + v0.z;
        int e4 = ex0.w + v0.w;
        ex1.x = e4;           ex1.y = ex1.x + v1.x;
        ex1.z = ex1.y + v1.y; ex1.w = ex1.z + v1.z;
        if (i0 < N4) { ((int4*)row_start)[i0] = ex0; ((int4*)cursor)[i0] = ex0; }
        if (i1 < N4) { ((int4*)row_start)[i1] = ex1; ((int4*)cursor)[i1] = ex1; }
        const int tot = wsum[15];
        __syncthreads();
        run += tot;
    }
    if (tid == 0) row_start[N_NODES] = run;
}

__global__ __launch_bounds__(256) void scatter_kernel(const int* __restrict__ ei,
                                                      int* __restrict__ cursor,
                                                      int* __restrict__ edge_src) {
    int e = blockIdx.x * 256 + threadIdx.x;
    if (e >= N_EDGE_T) return;
    int s, d;
    if (e < N_EDGE) { s = ei[e]; d = ei[N_EDGE + e]; }
    else            { s = d = e - N_EDGE; }
    int pos = atomicAdd(&cursor[d], 1);
    edge_src[pos] = s;
}

// ---------------- Layer 1 ----------------
// Block = 128 threads = 2 waves per dst node. 16 lanes per head:
// head = tid>>4, c4 = tid&15 -> 4 channels colb..colb+3.
// R5 theory: R1's s_load path (edge_src + x rows, uniform addresses) funnels
// every wave through the per-CU scalar cache; x (960 KB) misses K$ ~always and
// the shallow scalar miss path serializes ACROSS waves -> TLP can't hide it
// (VALUBusy 49% at ~20 waves/CU). Fix: force all in-loop loads onto the
// VECTOR path (L1, deep MSHRs, in-order vmcnt -> partial waits). An opaque
// VGPR zero poisons the edge_src base so the index load is VMEM; row loads
// use the VGPR index (uniform address -> HW broadcast, 1 txn/wave).

__device__ __forceinline__ float4 ld_row4(const float* __restrict__ x, int s, int o) {
    return *(const float4*)(x + s * IN_DIM + o);   // s in VGPR -> global_load_dwordx4
}

__global__ void __launch_bounds__(128, 3)   // min 3 waves/EU -> VGPR cap ~168
layer1_kernel(
    const float* __restrict__ x,
    const float* __restrict__ W1l, const float* __restrict__ W1r,
    const float* __restrict__ a1,  const float* __restrict__ b1,
    const float* __restrict__ W2l, const float* __restrict__ W2r,
    const int* __restrict__ row_start, const int* __restrict__ edge_src,
    float* __restrict__ xl2, float* __restrict__ xr2)
{
    const int d    = blockIdx.x;
    const int tid  = threadIdx.x;        // 0..127
    const int head = tid >> 4;           // 0..7
    const int c4   = tid & 15;
    const int colb = head * HIDDEN + c4 * 4;   // 4 contiguous columns

    // opaque per-lane zero: compiler cannot prove uniformity -> VMEM loads
    int vz; asm("v_mov_b32 %0, 0" : "=v"(vz));
    const int* __restrict__ es = edge_src + vz;

    float wl[IN_DIM][4], av[4];
    #pragma unroll
    for (int k = 0; k < IN_DIM; ++k) {
        const float4 l4 = *(const float4*)&W1l[k * 512 + colb];
        wl[k][0] = l4.x; wl[k][1] = l4.y; wl[k][2] = l4.z; wl[k][3] = l4.w;
    }
    { const float4 a4 = *(const float4*)&a1[colb];
      av[0] = a4.x; av[1] = a4.y; av[2] = a4.z; av[3] = a4.w; }

    // xr for destination node; W1r streamed (not kept resident)
    float xr[4] = {0.f, 0.f, 0.f, 0.f};
    #pragma unroll
    for (int k = 0; k < IN_DIM; ++k) {
        const float4 r4 = *(const float4*)&W1r[k * 512 + colb];
        const float xv = x[d * IN_DIM + k];
        xr[0] = fmaf(xv, r4.x, xr[0]); xr[1] = fmaf(xv, r4.y, xr[1]);
        xr[2] = fmaf(xv, r4.z, xr[2]); xr[3] = fmaf(xv, r4.w, xr[3]);
    }

    #pragma unroll
    for (int k = 0; k < IN_DIM; ++k) {
        PIN_V(wl[k][0]); PIN_V(wl[k][1]); PIN_V(wl[k][2]); PIN_V(wl[k][3]);
    }
    PIN_V(av[0]); PIN_V(av[1]); PIN_V(av[2]); PIN_V(av[3]);
    PIN_V(xr[0]); PIN_V(xr[1]); PIN_V(xr[2]); PIN_V(xr[3]);

    const int rs = row_start[d];
    const int re = row_start[d + 1];

    float denom  = 0.f;
    float acc[4] = {0.f, 0.f, 0.f, 0.f};   // acc' = sum p * (xl + xr)

    // two edges at a time, interleaved chains; v starts at xr (v-space)
    auto pair2 = [&](float4 a0, float4 a1_, float4 b0, float4 b1_,
                     bool va, bool vb) {
        const float ra[IN_DIM] = {a0.x, a0.y, a0.z, a0.w, a1_.x, a1_.y, a1_.z, a1_.w};
        const float rb[IN_DIM] = {b0.x, b0.y, b0.z, b0.w, b1_.x, b1_.y, b1_.z, b1_.w};
        float v0a = xr[0], v1a = xr[1], v2a = xr[2], v3a = xr[3];
        float v0b = xr[0], v1b = xr[1], v2b = xr[2], v3b = xr[3];
        #pragma unroll
        for (int k = 0; k < IN_DIM; ++k) {
            const float xa = ra[k], xb = rb[k];
            v0a = fmaf(xa, wl[k][0], v0a); v0b = fmaf(xb, wl[k][0], v0b);
            v1a = fmaf(xa, wl[k][1], v1a); v1b = fmaf(xb, wl[k][1], v1b);
            v2a = fmaf(xa, wl[k][2], v2a); v2b = fmaf(xb, wl[k][2], v2b);
            v3a = fmaf(xa, wl[k][3], v3a); v3b = fmaf(xb, wl[k][3], v3b);
        }
        float ta, tb, ea, eb;
        ta = fmaxf(v0a, NEG_SLOPE * v0a); ea = av[0] * ta;
        tb = fmaxf(v0b, NEG_SLOPE * v0b); eb = av[0] * tb;
        ta = fmaxf(v1a, NEG_SLOPE * v1a); ea = fmaf(av[1], ta, ea);
        tb = fmaxf(v1b, NEG_SLOPE * v1b); eb = fmaf(av[1], tb, eb);
        ta = fmaxf(v2a, NEG_SLOPE * v2a); ea = fmaf(av[2], ta, ea);
        tb = fmaxf(v2b, NEG_SLOPE * v2b); eb = fmaf(av[2], tb, eb);
        ta = fmaxf(v3a, NEG_SLOPE * v3a); ea = fmaf(av[3], ta, ea);
        tb = fmaxf(v3b, NEG_SLOPE * v3b); eb = fmaf(av[3], tb, eb);
        RED16(ea); RED16(eb);                     // pure VALU, no lgkm
        float pa = va ? __expf(ea) : 0.f;
        float pb = vb ? __expf(eb) : 0.f;
        denom += pa + pb;
        acc[0] = fmaf(pb, v0b, fmaf(pa, v0a, acc[0]));
        acc[1] = fmaf(pb, v1b, fmaf(pa, v1a, acc[1]));
        acc[2] = fmaf(pb, v2b, fmaf(pa, v2a, acc[2]));
        acc[3] = fmaf(pb, v3b, fmaf(pa, v3a, acc[3]));
    };

    // group 0: indices + rows, all VMEM
    float4 rA0, rA1, rB0, rB1, rC0, rC1, rD0, rD1;
    {
        int e1 = (rs + 1 < re) ? rs + 1 : re - 1;
        int e2 = (rs + 2 < re) ? rs + 2 : re - 1;
        int e3 = (rs + 3 < re) ? rs + 3 : re - 1;
        int s0 = es[rs], s1 = es[e1], s2 = es[e2], s3 = es[e3];
        rA0 = ld_row4(x, s0, 0); rA1 = ld_row4(x, s0, 4);
        rB0 = ld_row4(x, s1, 0); rB1 = ld_row4(x, s1, 4);
        rC0 = ld_row4(x, s2, 0); rC1 = ld_row4(x, s2, 4);
        rD0 = ld_row4(x, s3, 0); rD1 = ld_row4(x, s3, 4);
    }

    int base = rs;
    for (;;) {
        const int  nbase = base + 4;
        const bool more  = nbase < re;

        // issue next-group index loads (VMEM); consumed after pair2 #1
        int ns0 = 0, ns1 = 0, ns2 = 0, ns3 = 0;
        if (more) {
            int f1 = (nbase + 1 < re) ? nbase + 1 : re - 1;
            int f2 = (nbase + 2 < re) ? nbase + 2 : re - 1;
            int f3 = (nbase + 3 < re) ? nbase + 3 : re - 1;
            ns0 = es[nbase]; ns1 = es[f1]; ns2 = es[f2]; ns3 = es[f3];
        }

        pair2(rA0, rA1, rB0, rB1, true, base + 1 < re);

        // issue next-group row loads (VMEM); consumed at next iter's pair2 #1
        float4 nA0, nA1, nB0, nB1, nC0, nC1, nD0, nD1;
        if (more) {
            nA0 = ld_row4(x, ns0, 0); nA1 = ld_row4(x, ns0, 4);
            nB0 = ld_row4(x, ns1, 0); nB1 = ld_row4(x, ns1, 4);
            nC0 = ld_row4(x, ns2, 0); nC1 = ld_row4(x, ns2, 4);
            nD0 = ld_row4(x, ns3, 0); nD1 = ld_row4(x, ns3, 4);
        }

        pair2(rC0, rC1, rD0, rD1, base + 2 < re, base + 3 < re);

        if (!more) break;
        base = nbase;
        rA0 = nA0; rA1 = nA1; rB0 = nB0; rB1 = nB1;
        rC0 = nC0; rC1 = nC1; rD0 = nD0; rD1 = nD1;
    }

    const float inv = 1.f / denom;
    const float4 b4 = *(const float4*)&b1[colb];
    float hv[4];
    // acc'/denom - xr = true attention output; then +bias, ReLU
    hv[0] = fmaxf(fmaf(acc[0], inv, b4.x - xr[0]), 0.f);
    hv[1] = fmaxf(fmaf(acc[1], inv, b4.y - xr[1]), 0.f);
    hv[2] = fmaxf(fmaf(acc[2], inv, b4.z - xr[2]), 0.f);
    hv[3] = fmaxf(fmaf(acc[3], inv, b4.w - xr[3]), 0.f);

    // Epilogue: per-lane partials of h @ W2{l,r}, DPP-reduce over 16-lane
    // group, LDS finish across heads.
    float vl[OUT_DIM], vr[OUT_DIM];
    #pragma unroll
    for (int j = 0; j < OUT_DIM; ++j) { vl[j] = 0.f; vr[j] = 0.f; }
    #pragma unroll
    for (int i = 0; i < 4; ++i) {
        const float4 l0 = *(const float4*)&W2l[(colb + i) * OUT_DIM];
        const float4 l1 = *(const float4*)&W2l[(colb + i) * OUT_DIM + 4];
        const float4 r0 = *(const float4*)&W2r[(colb + i) * OUT_DIM];
        const float4 r1 = *(const float4*)&W2r[(colb + i) * OUT_DIM + 4];
        vl[0] = fmaf(hv[i], l0.x, vl[0]); vl[1] = fmaf(hv[i], l0.y, vl[1]);
        vl[2] = fmaf(hv[i], l0.z, vl[2]); vl[3] = fmaf(hv[i], l0.w, vl[3]);
        vl[4] = fmaf(hv[i], l1.x, vl[4]); vl[5] = fmaf(hv[i], l1.y, vl[5]);
        vl[6] = fmaf(hv[i], l1.z, vl[6]); vl[7] = fmaf(hv[i], l1.w, vl[7]);
        vr[0] = fmaf(hv[i], r0.x, vr[0]); vr[1] = fmaf(hv[i], r0.y, vr[1]);
        vr[2] = fmaf(hv[i], r0.z, vr[2]); vr[3] = fmaf(hv[i], r0.w, vr[3]);
        vr[4] = fmaf(hv[i], r1.x, vr[4]); vr[5] = fmaf(hv[i], r1.y, vr[5]);
        vr[6] = fmaf(hv[i], r1.z, vr[6]); vr[7] = fmaf(hv[i], r1.w, vr[7]);
    }
    #pragma unroll
    for (int j = 0; j < OUT_DIM; ++j) { RED16(vl[j]); RED16(vr[j]); }

    __shared__ float psl[HEADS][OUT_DIM];
    __shared__ float psr[HEADS][OUT_DIM];
    if (c4 == 0) {
        #pragma unroll
        for (int j = 0; j < OUT_DIM; ++j) { psl[head][j] = vl[j]; psr[head][j] = vr[j]; }
    }
    __syncthreads();
    if (tid < 16) {
        const int side = tid >> 3, j = tid & 7;
        float s = 0.f;
        if (side == 0) {
            #pragma unroll
            for (int h = 0; h < HEADS; ++h) s += psl[h][j];
            xl2[d * OUT_DIM + j] = s;
        } else {
            #pragma unroll
            for (int h = 0; h < HEADS; ++h) s += psr[h][j];
            xr2[d * OUT_DIM + j] = s;
        }
    }
}

// ---------------- Layer 2 (1 head, dim 8) ----------------

__global__ __launch_bounds__(256) void layer2_kernel(
    const float* __restrict__ xl2, const float* __restrict__ xr2,
    const float* __restrict__ a2,  const float* __restrict__ b2,
    const int* __restrict__ row_start, const int* __restrict__ edge_src,
    float* __restrict__ out)
{
    const int wave = threadIdx.x >> 6;
    const int lane = threadIdx.x & 63;
    const int d = blockIdx.x * 4 + wave;
    if (d >= N_NODES) return;
    const int sub = lane >> 3;   // edge slot 0..7
    const int c   = lane & 7;    // channel

    const float a_c  = a2[c];
    const float xr_d = xr2[d * OUT_DIM + c];

    const int rs = row_start[d];
    const int re = row_start[d + 1];

    float denom = 0.f, acc = 0.f;

    for (int base = rs; base < re; base += 8) {
        int e = base + sub;
        bool valid = (e < re);
        int s = valid ? edge_src[e] : 0;
        float xls = xl2[s * OUT_DIM + c];
        float v = xls + xr_d;
        float t = fmaxf(v, NEG_SLOPE * v);
        float eh = a_c * t;
        RED8(eh);                       // DPP: no lgkm in loop
        float p = valid ? __expf(eh) : 0.f;
        denom += p;
        acc = fmaf(p, xls, acc);
    }

    denom += __shfl_xor(denom, 8,  64);  acc += __shfl_xor(acc, 8,  64);
    denom += __shfl_xor(denom, 16, 64);  acc += __shfl_xor(acc, 16, 64);
    denom += __shfl_xor(denom, 32, 64);  acc += __shfl_xor(acc, 32, 64);

    if (sub == 0) out[d * OUT_DIM + c] = acc / denom + b2[c];
}

// ---------------- launch ----------------

extern "C" void kernel_launch(void* const* d_in, const int* in_sizes, int n_in,
                              void* d_out, int out_size, void* d_ws, size_t ws_size,
                              hipStream_t stream) {
    const float* x   = (const float*)d_in[0];
    const int*   ei  = (const int*)  d_in[1];
    const float* W1l = (const float*)d_in[2];
    const float* W1r = (const float*)d_in[3];
    const float* a1  = (const float*)d_in[4];
    const float* b1  = (const float*)d_in[5];
    const float* W2l = (const float*)d_in[6];
    const float* W2r = (const float*)d_in[7];
    const float* a2  = (const float*)d_in[8];
    const float* b2  = (const float*)d_in[9];
    float* out = (float*)d_out;

    char* ws = (char*)d_ws;
    size_t off = 0;
    auto carve = [&](size_t bytes) { char* p = ws + off; off += (bytes + 255) & ~size_t(255); return p; };
    int*   count     = (int*)  carve(N_NODES * sizeof(int));
    int*   row_start = (int*)  carve((N_NODES + 1) * sizeof(int));
    int*   cursor    = (int*)  carve(N_NODES * sizeof(int));
    int*   edge_src  = (int*)  carve(N_EDGE_T * sizeof(int));
    float* xl2       = (float*)carve(N_NODES * OUT_DIM * sizeof(float));
    float* xr2       = (float*)carve(N_NODES * OUT_DIM * sizeof(float));

    zero_kernel   <<<(N_NODES  + 255) / 256, 256, 0, stream>>>(count);
    count_kernel  <<<(N_EDGE_T + 255) / 256, 256, 0, stream>>>(ei, count);
    scan_kernel   <<<1, 1024, 0, stream>>>(count, row_start, cursor);
    scatter_kernel<<<(N_EDGE_T + 255) / 256, 256, 0, stream>>>(ei, cursor, edge_src);
    layer1_kernel <<<N_NODES, 128, 0, stream>>>(x, W1l, W1r, a1, b1, W2l, W2r,
                                                row_start, edge_src, xl2, xr2);
    layer2_kernel <<<(N_NODES + 3) / 4, 256, 0, stream>>>(xl2, xr2, a2, b2,
                                                          row_start, edge_src, out);
}

// Round 3
// 302.493 us; speedup vs baseline: 1.0148x; 1.0148x over previous
//
#include <hip/hip_runtime.h>
#include <math.h>

#define N_NODES   30000
#define N_EDGE    300000
#define N_EDGE_T  330000   // + self loops
#define HEADS     8
#define HIDDEN    64
#define IN_DIM    8
#define OUT_DIM   8
#define NEG_SLOPE 0.2f

#define PIN_V(v) asm volatile("" : "+v"(v))

// ---- DPP cross-lane reductions (pure VALU; no lgkmcnt) ----
#define DPP_ADDF(x, ctrl)                                                     \
    x += __int_as_float(__builtin_amdgcn_update_dpp(                          \
            0, __float_as_int(x), (ctrl), 0xF, 0xF, true))
// sum over aligned 16-lane group (all 16 lanes get the total):
#define RED16(x) do { DPP_ADDF(x, 0xB1); DPP_ADDF(x, 0x4E);                   \
                      DPP_ADDF(x, 0x141); DPP_ADDF(x, 0x140); } while (0)
// sum over aligned 8-lane group:
#define RED8(x)  do { DPP_ADDF(x, 0xB1); DPP_ADDF(x, 0x4E);                   \
                      DPP_ADDF(x, 0x141); } while (0)

// ---------------- CSR build ----------------

__global__ __launch_bounds__(256) void zero_kernel(int* __restrict__ count) {
    int i = blockIdx.x * 256 + threadIdx.x;
    if (i < N_NODES) count[i] = 0;
}

__global__ __launch_bounds__(256) void count_kernel(const int* __restrict__ ei,
                                                    int* __restrict__ count) {
    int e = blockIdx.x * 256 + threadIdx.x;
    if (e >= N_EDGE_T) return;
    int d = (e < N_EDGE) ? ei[N_EDGE + e] : (e - N_EDGE);
    atomicAdd(&count[d], 1);
}

// Single-block scan, 8 ints/thread via 2x int4: 4 rounds.
__global__ __launch_bounds__(1024) void scan_kernel(const int* __restrict__ count,
                                                    int* __restrict__ row_start,
                                                    int* __restrict__ cursor) {
    __shared__ int wsum[16];
    const int tid  = threadIdx.x;
    const int wave = tid >> 6;
    const int lane = tid & 63;
    const int4* c4 = (const int4*)count;
    const int N4 = N_NODES / 4;              // 7500 int4s exactly
    int run = 0;
    for (int r = 0; r < 4; ++r) {
        const int g  = r * 1024 + tid;       // thread-slot in round
        const int i0 = 2 * g;                // int4 idx of first half
        const int i1 = 2 * g + 1;
        int4 v0 = make_int4(0,0,0,0), v1 = make_int4(0,0,0,0);
        if (i0 < N4) v0 = c4[i0];
        if (i1 < N4) v1 = c4[i1];
        int s = v0.x + v0.y + v0.z + v0.w + v1.x + v1.y + v1.z + v1.w;
        int sc = s;
        #pragma unroll
        for (int off = 1; off < 64; off <<= 1) {
            int t = __shfl_up(sc, off, 64);
            if (lane >= off) sc += t;
        }
        if (lane == 63) wsum[wave] = sc;
        __syncthreads();
        if (tid < 16) {
            int w = wsum[tid];
            #pragma unroll
            for (int off = 1; off < 16; off <<= 1) {
                int t = __shfl_up(w, off, 64);
                if (tid >= off) w += t;
            }
            wsum[tid] = w;
        }
        __syncthreads();
        const int woff = (wave > 0) ? wsum[wave - 1] : 0;
        int e0 = run + woff + (sc - s);       // exclusive prefix of this thread's 8
        int4 ex0, ex1;
        ex0.x = e0;           ex0.y = ex0.x + v0.x;
        ex0.z = ex0.y + v0.y; ex0.w = ex0.z + v0.z;
        int e4 = ex0.w + v0.w;
        ex1.x = e4;           ex1.y = ex1.x + v1.x;
        ex1.z = ex1.y + v1.y; ex1.w = ex1.z + v1.z;
        if (i0 < N4) { ((int4*)row_start)[i0] = ex0; ((int4*)cursor)[i0] = ex0; }
        if (i1 < N4) { ((int4*)row_start)[i1] = ex1; ((int4*)cursor)[i1] = ex1; }
        const int tot = wsum[15];
        __syncthreads();
        run += tot;
    }
    if (tid == 0) row_start[N_NODES] = run;
}

__global__ __launch_bounds__(256) void scatter_kernel(const int* __restrict__ ei,
                                                      int* __restrict__ cursor,
                                                      int* __restrict__ edge_src) {
    int e = blockIdx.x * 256 + threadIdx.x;
    if (e >= N_EDGE_T) return;
    int s, d;
    if (e < N_EDGE) { s = ei[e]; d = ei[N_EDGE + e]; }
    else            { s = d = e - N_EDGE; }
    int pos = atomicAdd(&cursor[d], 1);
    edge_src[pos] = s;
}

// ---------------- Projection precompute (R3) ----------------
// R0-R2 lesson: layer1 recomputed x[src]@W1l per EDGE (avg degree 11 ->
// 11x redundant FMA; 1.35G MAC total, the dominant VALU cost at ~45% duty).
// Project once per NODE here (0.12G MAC, ~3us VALU + 61MB stream), then
// layer1 gathers xl[src] as one per-lane float4 (lane-divergent -> true
// vector load; 1KB contiguous per wave per edge; table is L2/L3-resident).

__global__ __launch_bounds__(256) void proj_kernel(
    const float* __restrict__ x, const float* __restrict__ W1l,
    float* __restrict__ xl_t)
{
    const int t = threadIdx.x;           // 0..255; cols t and t+256
    float wl0[IN_DIM], wl1[IN_DIM];
    #pragma unroll
    for (int k = 0; k < IN_DIM; ++k) {
        wl0[k] = W1l[k * 512 + t];
        wl1[k] = W1l[k * 512 + t + 256];
    }
    for (int n = blockIdx.x; n < N_NODES; n += gridDim.x) {
        float xv[IN_DIM];
        #pragma unroll
        for (int k = 0; k < IN_DIM; ++k) xv[k] = x[n * IN_DIM + k];  // uniform -> s_load
        float l0 = 0.f, l1 = 0.f;
        #pragma unroll
        for (int k = 0; k < IN_DIM; ++k) {
            l0 = fmaf(xv[k], wl0[k], l0);
            l1 = fmaf(xv[k], wl1[k], l1);
        }
        xl_t[n * 512 + t]       = l0;
        xl_t[n * 512 + t + 256] = l1;
    }
}

// ---------------- Layer 1 ----------------
// Block = 128 threads = 2 waves per dst node. 16 lanes per head:
// head = tid>>4, c4 = tid&15 -> 4 channels colb..colb+3.
// Loop body per edge: 1 float4 gather of xl[src] + ~22 VALU (add, leaky,
// dot, RED16, exp, acc). Indices on the scalar path (uniform, one s_load
// group prefetched one group ahead); rows on the vector path (divergent).

__global__ void __launch_bounds__(128, 4)
layer1_kernel(
    const float* __restrict__ x,
    const float* __restrict__ xl_t, const float* __restrict__ W1r,
    const float* __restrict__ a1,  const float* __restrict__ b1,
    const float* __restrict__ W2l, const float* __restrict__ W2r,
    const int* __restrict__ row_start, const int* __restrict__ edge_src,
    float* __restrict__ xl2, float* __restrict__ xr2)
{
    const int d    = blockIdx.x;
    const int tid  = threadIdx.x;        // 0..127
    const int head = tid >> 4;           // 0..7
    const int c4   = tid & 15;
    const int colb = head * HIDDEN + c4 * 4;   // 4 contiguous columns

    float av[4];
    { const float4 a4 = *(const float4*)&a1[colb];
      av[0] = a4.x; av[1] = a4.y; av[2] = a4.z; av[3] = a4.w; }

    // xr for destination node, computed once (W1r streamed, L2-hot)
    float xrv[4] = {0.f, 0.f, 0.f, 0.f};
    #pragma unroll
    for (int k = 0; k < IN_DIM; ++k) {
        const float4 r4 = *(const float4*)&W1r[k * 512 + colb];
        const float xv = x[d * IN_DIM + k];
        xrv[0] = fmaf(xv, r4.x, xrv[0]); xrv[1] = fmaf(xv, r4.y, xrv[1]);
        xrv[2] = fmaf(xv, r4.z, xrv[2]); xrv[3] = fmaf(xv, r4.w, xrv[3]);
    }
    PIN_V(av[0]); PIN_V(av[1]); PIN_V(av[2]); PIN_V(av[3]);
    PIN_V(xrv[0]); PIN_V(xrv[1]); PIN_V(xrv[2]); PIN_V(xrv[3]);

    const int rs = row_start[d];
    const int re = row_start[d + 1];

    float denom  = 0.f;
    float acc[4] = {0.f, 0.f, 0.f, 0.f};   // sum p * xl[src]

    auto ldrow = [&](int s) { return *(const float4*)&xl_t[s * 512 + colb]; };

    // two edges at a time; row values ARE the xl fragments (gathered)
    auto pair2 = [&](float4 ra, float4 rb, bool va, bool vb) {
        float q0a = ra.x + xrv[0], q1a = ra.y + xrv[1];
        float q2a = ra.z + xrv[2], q3a = ra.w + xrv[3];
        float q0b = rb.x + xrv[0], q1b = rb.y + xrv[1];
        float q2b = rb.z + xrv[2], q3b = rb.w + xrv[3];
        float ta, tb, ea, eb;
        ta = fmaxf(q0a, NEG_SLOPE * q0a); ea = av[0] * ta;
        tb = fmaxf(q0b, NEG_SLOPE * q0b); eb = av[0] * tb;
        ta = fmaxf(q1a, NEG_SLOPE * q1a); ea = fmaf(av[1], ta, ea);
        tb = fmaxf(q1b, NEG_SLOPE * q1b); eb = fmaf(av[1], tb, eb);
        ta = fmaxf(q2a, NEG_SLOPE * q2a); ea = fmaf(av[2], ta, ea);
        tb = fmaxf(q2b, NEG_SLOPE * q2b); eb = fmaf(av[2], tb, eb);
        ta = fmaxf(q3a, NEG_SLOPE * q3a); ea = fmaf(av[3], ta, ea);
        tb = fmaxf(q3b, NEG_SLOPE * q3b); eb = fmaf(av[3], tb, eb);
        RED16(ea); RED16(eb);                     // pure VALU
        float pa = va ? __expf(ea) : 0.f;
        float pb = vb ? __expf(eb) : 0.f;
        denom += pa + pb;
        acc[0] = fmaf(pb, rb.x, fmaf(pa, ra.x, acc[0]));
        acc[1] = fmaf(pb, rb.y, fmaf(pa, ra.y, acc[1]));
        acc[2] = fmaf(pb, rb.z, fmaf(pa, ra.z, acc[2]));
        acc[3] = fmaf(pb, rb.w, fmaf(pa, ra.w, acc[3]));
    };

    // group 0: indices (scalar) + rows (vector)
    float4 rA, rB, rC, rD;
    {
        int e1 = (rs + 1 < re) ? rs + 1 : re - 1;
        int e2 = (rs + 2 < re) ? rs + 2 : re - 1;
        int e3 = (rs + 3 < re) ? rs + 3 : re - 1;
        int s0 = edge_src[rs], s1 = edge_src[e1];
        int s2 = edge_src[e2], s3 = edge_src[e3];
        rA = ldrow(s0); rB = ldrow(s1); rC = ldrow(s2); rD = ldrow(s3);
    }

    int base = rs;
    for (;;) {
        const int  nbase = base + 4;
        const bool more  = nbase < re;

        // next-group index loads (scalar); consumed after pair2 #1
        int ns0 = 0, ns1 = 0, ns2 = 0, ns3 = 0;
        if (more) {
            int f1 = (nbase + 1 < re) ? nbase + 1 : re - 1;
            int f2 = (nbase + 2 < re) ? nbase + 2 : re - 1;
            int f3 = (nbase + 3 < re) ? nbase + 3 : re - 1;
            ns0 = edge_src[nbase]; ns1 = edge_src[f1];
            ns2 = edge_src[f2];    ns3 = edge_src[f3];
        }

        pair2(rA, rB, true, base + 1 < re);

        // next-group row gathers (vector); consumed next iteration
        float4 nA, nB, nC, nD;
        if (more) {
            nA = ldrow(ns0); nB = ldrow(ns1); nC = ldrow(ns2); nD = ldrow(ns3);
        }

        pair2(rC, rD, base + 2 < re, base + 3 < re);

        if (!more) break;
        base = nbase;
        rA = nA; rB = nB; rC = nC; rD = nD;
    }

    const float inv = 1.f / denom;
    const float4 b4 = *(const float4*)&b1[colb];
    float hv[4];
    hv[0] = fmaxf(fmaf(acc[0], inv, b4.x), 0.f);
    hv[1] = fmaxf(fmaf(acc[1], inv, b4.y), 0.f);
    hv[2] = fmaxf(fmaf(acc[2], inv, b4.z), 0.f);
    hv[3] = fmaxf(fmaf(acc[3], inv, b4.w), 0.f);

    // Epilogue: per-lane partials of h @ W2{l,r}, DPP-reduce over 16-lane
    // group, LDS finish across heads.
    float vl[OUT_DIM], vr[OUT_DIM];
    #pragma unroll
    for (int j = 0; j < OUT_DIM; ++j) { vl[j] = 0.f; vr[j] = 0.f; }
    #pragma unroll
    for (int i = 0; i < 4; ++i) {
        const float4 l0 = *(const float4*)&W2l[(colb + i) * OUT_DIM];
        const float4 l1 = *(const float4*)&W2l[(colb + i) * OUT_DIM + 4];
        const float4 r0 = *(const float4*)&W2r[(colb + i) * OUT_DIM];
        const float4 r1 = *(const float4*)&W2r[(colb + i) * OUT_DIM + 4];
        vl[0] = fmaf(hv[i], l0.x, vl[0]); vl[1] = fmaf(hv[i], l0.y, vl[1]);
        vl[2] = fmaf(hv[i], l0.z, vl[2]); vl[3] = fmaf(hv[i], l0.w, vl[3]);
        vl[4] = fmaf(hv[i], l1.x, vl[4]); vl[5] = fmaf(hv[i], l1.y, vl[5]);
        vl[6] = fmaf(hv[i], l1.z, vl[6]); vl[7] = fmaf(hv[i], l1.w, vl[7]);
        vr[0] = fmaf(hv[i], r0.x, vr[0]); vr[1] = fmaf(hv[i], r0.y, vr[1]);
        vr[2] = fmaf(hv[i], r0.z, vr[2]); vr[3] = fmaf(hv[i], r0.w, vr[3]);
        vr[4] = fmaf(hv[i], r1.x, vr[4]); vr[5] = fmaf(hv[i], r1.y, vr[5]);
        vr[6] = fmaf(hv[i], r1.z, vr[6]); vr[7] = fmaf(hv[i], r1.w, vr[7]);
    }
    #pragma unroll
    for (int j = 0; j < OUT_DIM; ++j) { RED16(vl[j]); RED16(vr[j]); }

    __shared__ float psl[HEADS][OUT_DIM];
    __shared__ float psr[HEADS][OUT_DIM];
    if (c4 == 0) {
        #pragma unroll
        for (int j = 0; j < OUT_DIM; ++j) { psl[head][j] = vl[j]; psr[head][j] = vr[j]; }
    }
    __syncthreads();
    if (tid < 16) {
        const int side = tid >> 3, j = tid & 7;
        float s = 0.f;
        if (side == 0) {
            #pragma unroll
            for (int h = 0; h < HEADS; ++h) s += psl[h][j];
            xl2[d * OUT_DIM + j] = s;
        } else {
            #pragma unroll
            for (int h = 0; h < HEADS; ++h) s += psr[h][j];
            xr2[d * OUT_DIM + j] = s;
        }
    }
}

// ---------------- Layer 2 (1 head, dim 8) ----------------

__global__ __launch_bounds__(256) void layer2_kernel(
    const float* __restrict__ xl2, const float* __restrict__ xr2,
    const float* __restrict__ a2,  const float* __restrict__ b2,
    const int* __restrict__ row_start, const int* __restrict__ edge_src,
    float* __restrict__ out)
{
    const int wave = threadIdx.x >> 6;
    const int lane = threadIdx.x & 63;
    const int d = blockIdx.x * 4 + wave;
    if (d >= N_NODES) return;
    const int sub = lane >> 3;   // edge slot 0..7
    const int c   = lane & 7;    // channel

    const float a_c  = a2[c];
    const float xr_d = xr2[d * OUT_DIM + c];

    const int rs = row_start[d];
    const int re = row_start[d + 1];

    float denom = 0.f, acc = 0.f;

    for (int base = rs; base < re; base += 8) {
        int e = base + sub;
        bool valid = (e < re);
        int s = valid ? edge_src[e] : 0;
        float xls = xl2[s * OUT_DIM + c];
        float v = xls + xr_d;
        float t = fmaxf(v, NEG_SLOPE * v);
        float eh = a_c * t;
        RED8(eh);                       // DPP: no lgkm in loop
        float p = valid ? __expf(eh) : 0.f;
        denom += p;
        acc = fmaf(p, xls, acc);
    }

    denom += __shfl_xor(denom, 8,  64);  acc += __shfl_xor(acc, 8,  64);
    denom += __shfl_xor(denom, 16, 64);  acc += __shfl_xor(acc, 16, 64);
    denom += __shfl_xor(denom, 32, 64);  acc += __shfl_xor(acc, 32, 64);

    if (sub == 0) out[d * OUT_DIM + c] = acc / denom + b2[c];
}

// ---------------- launch ----------------

extern "C" void kernel_launch(void* const* d_in, const int* in_sizes, int n_in,
                              void* d_out, int out_size, void* d_ws, size_t ws_size,
                              hipStream_t stream) {
    const float* x   = (const float*)d_in[0];
    const int*   ei  = (const int*)  d_in[1];
    const float* W1l = (const float*)d_in[2];
    const float* W1r = (const float*)d_in[3];
    const float* a1  = (const float*)d_in[4];
    const float* b1  = (const float*)d_in[5];
    const float* W2l = (const float*)d_in[6];
    const float* W2r = (const float*)d_in[7];
    const float* a2  = (const float*)d_in[8];
    const float* b2  = (const float*)d_in[9];
    float* out = (float*)d_out;

    char* ws = (char*)d_ws;
    size_t off = 0;
    auto carve = [&](size_t bytes) { char* p = ws + off; off += (bytes + 255) & ~size_t(255); return p; };
    int*   count     = (int*)  carve(N_NODES * sizeof(int));
    int*   row_start = (int*)  carve((N_NODES + 1) * sizeof(int));
    int*   cursor    = (int*)  carve(N_NODES * sizeof(int));
    int*   edge_src  = (int*)  carve(N_EDGE_T * sizeof(int));
    float* xl2       = (float*)carve(N_NODES * OUT_DIM * sizeof(float));
    float* xr2       = (float*)carve(N_NODES * OUT_DIM * sizeof(float));
    float* xl_t      = (float*)carve((size_t)N_NODES * 512 * sizeof(float)); // 61.4MB

    proj_kernel   <<<1024, 256, 0, stream>>>(x, W1l, xl_t);
    zero_kernel   <<<(N_NODES  + 255) / 256, 256, 0, stream>>>(count);
    count_kernel  <<<(N_EDGE_T + 255) / 256, 256, 0, stream>>>(ei, count);
    scan_kernel   <<<1, 1024, 0, stream>>>(count, row_start, cursor);
    scatter_kernel<<<(N_EDGE_T + 255) / 256, 256, 0, stream>>>(ei, cursor, edge_src);
    layer1_kernel <<<N_NODES, 128, 0, stream>>>(x, xl_t, W1r, a1, b1, W2l, W2r,
                                                row_start, edge_src, xl2, xr2);
    layer2_kernel <<<(N_NODES + 3) / 4, 256, 0, stream>>>(xl2, xr2, a2, b2,
                                                          row_start, edge_src, out);
}

// Round 6
// 299.503 us; speedup vs baseline: 1.0250x; 1.0100x over previous
//
#include <hip/hip_runtime.h>
#include <hip/hip_fp16.h>
#include <math.h>

#define N_NODES   30000
#define N_EDGE    300000
#define N_EDGE_T  330000   // + self loops
#define HEADS     8
#define HIDDEN    64
#define IN_DIM    8
#define OUT_DIM   8
#define NEG_SLOPE 0.2f

// ---- DPP cross-lane reductions (pure VALU; no lgkmcnt) ----
#define DPP_ADDF(x, ctrl)                                                     \
    x += __int_as_float(__builtin_amdgcn_update_dpp(                          \
            0, __float_as_int(x), (ctrl), 0xF, 0xF, true))
// sum over aligned 16-lane group:
#define RED16(x) do { DPP_ADDF(x, 0xB1); DPP_ADDF(x, 0x4E);                   \
                      DPP_ADDF(x, 0x141); DPP_ADDF(x, 0x140); } while (0)
// sum over aligned 8-lane group:
#define RED8(x)  do { DPP_ADDF(x, 0xB1); DPP_ADDF(x, 0x4E);                   \
                      DPP_ADDF(x, 0x141); } while (0)

// ---------------- CSR build ----------------

__global__ __launch_bounds__(256) void zero_kernel(int* __restrict__ count) {
    int i = blockIdx.x * 256 + threadIdx.x;
    if (i < N_NODES) count[i] = 0;
}

__global__ __launch_bounds__(256) void count_kernel(const int* __restrict__ ei,
                                                    int* __restrict__ count) {
    int e = blockIdx.x * 256 + threadIdx.x;
    if (e >= N_EDGE_T) return;
    int d = (e < N_EDGE) ? ei[N_EDGE + e] : (e - N_EDGE);
    atomicAdd(&count[d], 1);
}

// Single-block scan, 8 ints/thread via 2x int4: 4 rounds.
__global__ __launch_bounds__(1024) void scan_kernel(const int* __restrict__ count,
                                                    int* __restrict__ row_start,
                                                    int* __restrict__ cursor) {
    __shared__ int wsum[16];
    const int tid  = threadIdx.x;
    const int wave = tid >> 6;
    const int lane = tid & 63;
    const int4* c4 = (const int4*)count;
    const int N4 = N_NODES / 4;              // 7500 int4s exactly
    int run = 0;
    for (int r = 0; r < 4; ++r) {
        const int g  = r * 1024 + tid;       // thread-slot in round
        const int i0 = 2 * g;                // int4 idx of first half
        const int i1 = 2 * g + 1;
        int4 v0 = make_int4(0,0,0,0), v1 = make_int4(0,0,0,0);
        if (i0 < N4) v0 = c4[i0];
        if (i1 < N4) v1 = c4[i1];
        int s = v0.x + v0.y + v0.z + v0.w + v1.x + v1.y + v1.z + v1.w;
        int sc = s;
        #pragma unroll
        for (int off = 1; off < 64; off <<= 1) {
            int t = __shfl_up(sc, off, 64);
            if (lane >= off) sc += t;
        }
        if (lane == 63) wsum[wave] = sc;
        __syncthreads();
        if (tid < 16) {
            int w = wsum[tid];
            #pragma unroll
            for (int off = 1; off < 16; off <<= 1) {
                int t = __shfl_up(w, off, 64);
                if (tid >= off) w += t;
            }
            wsum[tid] = w;
        }
        __syncthreads();
        const int woff = (wave > 0) ? wsum[wave - 1] : 0;
        int e0 = run + woff + (sc - s);       // exclusive prefix of this thread's 8
        int4 ex0, ex1;
        ex0.x = e0;           ex0.y = ex0.x + v0.x;
        ex0.z = ex0.y + v0.y; ex0.w = ex0.z + v0.z;
        int e4 = ex0.w + v0.w;
        ex1.x = e4;           ex1.y = ex1.x + v1.x;
        ex1.z = ex1.y + v1.y; ex1.w = ex1.z + v1.z;
        if (i0 < N4) { ((int4*)row_start)[i0] = ex0; ((int4*)cursor)[i0] = ex0; }
        if (i1 < N4) { ((int4*)row_start)[i1] = ex1; ((int4*)cursor)[i1] = ex1; }
        const int tot = wsum[15];
        __syncthreads();
        run += tot;
    }
    if (tid == 0) row_start[N_NODES] = run;
}

__global__ __launch_bounds__(256) void scatter_kernel(const int* __restrict__ ei,
                                                      int* __restrict__ cursor,
                                                      int* __restrict__ edge_src) {
    int e = blockIdx.x * 256 + threadIdx.x;
    if (e >= N_EDGE_T) return;
    int s, d;
    if (e < N_EDGE) { s = ei[e]; d = ei[N_EDGE + e]; }
    else            { s = d = e - N_EDGE; }
    int pos = atomicAdd(&cursor[d], 1);
    edge_src[pos] = s;
}

// ---------------- Projection precompute (fp16) ----------------
// xl = x @ W1l once per node, packed half2: 1KB/row, 30.7MB table.
// Halves per-edge gather traffic vs fp32 (R3: 315MB HBM fetch).

__global__ __launch_bounds__(256) void proj_kernel(
    const float* __restrict__ x, const float* __restrict__ W1l,
    __half* __restrict__ xl_h)
{
    const int t = threadIdx.x;           // col pair (2t, 2t+1)
    float w0[IN_DIM], w1[IN_DIM];
    #pragma unroll
    for (int k = 0; k < IN_DIM; ++k) {
        const float2 wp = *(const float2*)&W1l[k * 512 + 2 * t];
        w0[k] = wp.x; w1[k] = wp.y;
    }
    for (int n = blockIdx.x; n < N_NODES; n += gridDim.x) {
        float xv[IN_DIM];
        #pragma unroll
        for (int k = 0; k < IN_DIM; ++k) xv[k] = x[n * IN_DIM + k];  // uniform -> s_load
        float l0 = 0.f, l1 = 0.f;
        #pragma unroll
        for (int k = 0; k < IN_DIM; ++k) {
            l0 = fmaf(xv[k], w0[k], l0);
            l1 = fmaf(xv[k], w1[k], l1);
        }
        ((__half2*)xl_h)[n * 256 + t] = __floats2half2_rn(l0, l1);
    }
}

// ---------------- Layer 1 (R6: 1 wave = 1 node, 4 nodes/block) ----------------
// R0-R3 invariant: ~160-175us regardless of loop content, neither pipe >50%
// busy -> structural floor suspected (30000 blocks, 2 coupled waves/node,
// duplicated scalar work, LDS+barrier epilogue). R6 structure:
//   lane l owns cols [8l, 8l+8); per edge ONE coalesced 16B/lane int4 load
//   covers the full 1KB fp16 row; head group = 8 lanes -> RED8 logit reduce;
//   no LDS, no __syncthreads anywhere; grid 7500x256; plain C++ only
//   (two crashed rounds of inline-asm loads -> dropped).

__global__ void __launch_bounds__(256, 4)
layer1_kernel(
    const float* __restrict__ x,
    const __half* __restrict__ xl_h, const float* __restrict__ W1r,
    const float* __restrict__ a1,  const float* __restrict__ b1,
    const float* __restrict__ W2l, const float* __restrict__ W2r,
    const int* __restrict__ row_start, const int* __restrict__ edge_src,
    float* __restrict__ xl2, float* __restrict__ xr2)
{
    const int wv   = threadIdx.x >> 6;     // 0..3
    const int lane = threadIdx.x & 63;
    const int d    = blockIdx.x * 4 + wv;  // 30000 = 7500*4 exactly
    const int colb = lane * 8;             // 8 contiguous columns per lane

    // attention vector + xr for destination node (W1r/a1 small, L2-hot)
    float av[8], xr[8];
    { const float4 a0 = *(const float4*)&a1[colb];
      const float4 a4 = *(const float4*)&a1[colb + 4];
      av[0]=a0.x; av[1]=a0.y; av[2]=a0.z; av[3]=a0.w;
      av[4]=a4.x; av[5]=a4.y; av[6]=a4.z; av[7]=a4.w; }
    #pragma unroll
    for (int i = 0; i < 8; ++i) xr[i] = 0.f;
    #pragma unroll
    for (int k = 0; k < IN_DIM; ++k) {
        const float4 r0 = *(const float4*)&W1r[k * 512 + colb];
        const float4 r4 = *(const float4*)&W1r[k * 512 + colb + 4];
        const float xv = x[d * IN_DIM + k];
        xr[0] = fmaf(xv, r0.x, xr[0]); xr[1] = fmaf(xv, r0.y, xr[1]);
        xr[2] = fmaf(xv, r0.z, xr[2]); xr[3] = fmaf(xv, r0.w, xr[3]);
        xr[4] = fmaf(xv, r4.x, xr[4]); xr[5] = fmaf(xv, r4.y, xr[5]);
        xr[6] = fmaf(xv, r4.z, xr[6]); xr[7] = fmaf(xv, r4.w, xr[7]);
    }

    const int rs = row_start[d];
    const int re = row_start[d + 1];

    float denom  = 0.f;
    float acc[8] = {0.f,0.f,0.f,0.f,0.f,0.f,0.f,0.f};

    // 16B coalesced fp16 row-fragment load
    auto ldrow = [&](int s, float (&o)[8]) {
        const int4 r = *(const int4*)(xl_h + (size_t)s * 512 + colb);
        union { int i; __half2 h; } u0, u1, u2, u3;
        u0.i = r.x; u1.i = r.y; u2.i = r.z; u3.i = r.w;
        float2 f;
        f = __half22float2(u0.h); o[0] = f.x; o[1] = f.y;
        f = __half22float2(u1.h); o[2] = f.x; o[3] = f.y;
        f = __half22float2(u2.h); o[4] = f.x; o[5] = f.y;
        f = __half22float2(u3.h); o[6] = f.x; o[7] = f.y;
    };

    auto edge1 = [&](const float (&rr)[8], bool valid) {
        float e = 0.f;
        #pragma unroll
        for (int i = 0; i < 8; ++i) {
            const float q = rr[i] + xr[i];
            const float t = fmaxf(q, NEG_SLOPE * q);
            e = fmaf(av[i], t, e);
        }
        RED8(e);                               // head group = 8 lanes
        const float p = valid ? __expf(e) : 0.f;
        denom += p;
        #pragma unroll
        for (int i = 0; i < 8; ++i) acc[i] = fmaf(p, rr[i], acc[i]);
    };

    // 2-edge groups, one group prefetched ahead (plain C++; with the 128-VGPR
    // budget the compiler can keep 4 row-loads in flight with counted waits)
    float RA[8], RB[8];
    {
        const int sA = edge_src[rs];
        const bool vB0 = rs + 1 < re;
        const int sB = edge_src[vB0 ? rs + 1 : rs];
        ldrow(sA, RA); ldrow(sB, RB);
    }
    bool vB = rs + 1 < re;

    for (int base = rs;;) {
        const int  nb   = base + 2;
        const bool more = nb < re;
        float RC[8], RD[8];
        bool vD = false;
        if (more) {
            const int sC = edge_src[nb];
            vD = nb + 1 < re;
            const int sD = edge_src[vD ? nb + 1 : nb];
            ldrow(sC, RC); ldrow(sD, RD);
        }
        edge1(RA, true);
        edge1(RB, vB);
        if (!more) break;
        #pragma unroll
        for (int i = 0; i < 8; ++i) { RA[i] = RC[i]; RB[i] = RD[i]; }
        vB = vD;
        base = nb;
    }

    // h = relu(acc/denom + b1)
    const float inv = 1.f / denom;
    float hv[8];
    { const float4 b0 = *(const float4*)&b1[colb];
      const float4 b4 = *(const float4*)&b1[colb + 4];
      hv[0] = fmaxf(fmaf(acc[0], inv, b0.x), 0.f);
      hv[1] = fmaxf(fmaf(acc[1], inv, b0.y), 0.f);
      hv[2] = fmaxf(fmaf(acc[2], inv, b0.z), 0.f);
      hv[3] = fmaxf(fmaf(acc[3], inv, b0.w), 0.f);
      hv[4] = fmaxf(fmaf(acc[4], inv, b4.x), 0.f);
      hv[5] = fmaxf(fmaf(acc[5], inv, b4.y), 0.f);
      hv[6] = fmaxf(fmaf(acc[6], inv, b4.z), 0.f);
      hv[7] = fmaxf(fmaf(acc[7], inv, b4.w), 0.f); }

    // Epilogue: h @ W2{l,r} entirely in-wave (no LDS, no barrier).
    float vl[OUT_DIM], vr[OUT_DIM];
    #pragma unroll
    for (int j = 0; j < OUT_DIM; ++j) { vl[j] = 0.f; vr[j] = 0.f; }
    #pragma unroll
    for (int i = 0; i < 8; ++i) {
        const int c = colb + i;
        const float4 l0 = *(const float4*)&W2l[c * OUT_DIM];
        const float4 l1 = *(const float4*)&W2l[c * OUT_DIM + 4];
        const float4 r0 = *(const float4*)&W2r[c * OUT_DIM];
        const float4 r1 = *(const float4*)&W2r[c * OUT_DIM + 4];
        const float h = hv[i];
        vl[0] = fmaf(h, l0.x, vl[0]); vl[1] = fmaf(h, l0.y, vl[1]);
        vl[2] = fmaf(h, l0.z, vl[2]); vl[3] = fmaf(h, l0.w, vl[3]);
        vl[4] = fmaf(h, l1.x, vl[4]); vl[5] = fmaf(h, l1.y, vl[5]);
        vl[6] = fmaf(h, l1.z, vl[6]); vl[7] = fmaf(h, l1.w, vl[7]);
        vr[0] = fmaf(h, r0.x, vr[0]); vr[1] = fmaf(h, r0.y, vr[1]);
        vr[2] = fmaf(h, r0.z, vr[2]); vr[3] = fmaf(h, r0.w, vr[3]);
        vr[4] = fmaf(h, r1.x, vr[4]); vr[5] = fmaf(h, r1.y, vr[5]);
        vr[6] = fmaf(h, r1.z, vr[6]); vr[7] = fmaf(h, r1.w, vr[7]);
    }
    // full-wave reduce: RED16 (xor 1,2,4,8) then xor 16, 32
    #pragma unroll
    for (int j = 0; j < OUT_DIM; ++j) {
        RED16(vl[j]);
        vl[j] += __shfl_xor(vl[j], 16, 64);
        vl[j] += __shfl_xor(vl[j], 32, 64);
        RED16(vr[j]);
        vr[j] += __shfl_xor(vr[j], 16, 64);
        vr[j] += __shfl_xor(vr[j], 32, 64);
    }
    if (lane == 0) {
        *(float4*)&xl2[d * OUT_DIM]     = make_float4(vl[0], vl[1], vl[2], vl[3]);
        *(float4*)&xl2[d * OUT_DIM + 4] = make_float4(vl[4], vl[5], vl[6], vl[7]);
        *(float4*)&xr2[d * OUT_DIM]     = make_float4(vr[0], vr[1], vr[2], vr[3]);
        *(float4*)&xr2[d * OUT_DIM + 4] = make_float4(vr[4], vr[5], vr[6], vr[7]);
    }
}

// ---------------- Layer 2 (1 head, dim 8) ----------------
// Common case (deg<=16, ~94% of Poisson-11 nodes): both 8-edge groups
// straight-line so their idx+gather chains overlap. Rare tail loops.

__global__ __launch_bounds__(256) void layer2_kernel(
    const float* __restrict__ xl2, const float* __restrict__ xr2,
    const float* __restrict__ a2,  const float* __restrict__ b2,
    const int* __restrict__ row_start, const int* __restrict__ edge_src,
    float* __restrict__ out)
{
    const int wave = threadIdx.x >> 6;
    const int lane = threadIdx.x & 63;
    const int d = blockIdx.x * 4 + wave;
    if (d >= N_NODES) return;
    const int sub = lane >> 3;   // edge slot 0..7
    const int c   = lane & 7;    // channel

    const float a_c  = a2[c];
    const float xr_d = xr2[d * OUT_DIM + c];

    const int rs = row_start[d];
    const int re = row_start[d + 1];

    // groups 0 and 1 upfront, loads in flight together
    int  e0 = rs + sub;      const bool v0 = e0 < re; e0 = v0 ? e0 : re - 1;
    int  e1 = rs + 8 + sub;  const bool v1 = e1 < re; e1 = v1 ? e1 : re - 1;
    const int s0 = edge_src[e0];
    const int s1 = edge_src[e1];
    const float x0 = xl2[s0 * OUT_DIM + c];
    const float x1 = xl2[s1 * OUT_DIM + c];

    const float u0 = x0 + xr_d; const float t0 = fmaxf(u0, NEG_SLOPE * u0);
    const float u1 = x1 + xr_d; const float t1 = fmaxf(u1, NEG_SLOPE * u1);
    float g0 = a_c * t0;
    float g1 = a_c * t1;
    RED8(g0); RED8(g1);                      // independent DPP chains
    const float p0 = v0 ? __expf(g0) : 0.f;
    const float p1 = v1 ? __expf(g1) : 0.f;
    float denom = p0 + p1;
    float acc   = fmaf(p1, x1, p0 * x0);

    // rare tail: deg > 16
    for (int b = rs + 16; b < re; b += 8) {
        int e = b + sub;
        const bool v = e < re; e = v ? e : re - 1;
        const int s = edge_src[e];
        const float xs = xl2[s * OUT_DIM + c];
        const float u = xs + xr_d;
        const float t = fmaxf(u, NEG_SLOPE * u);
        float g = a_c * t;
        RED8(g);
        const float p = v ? __expf(g) : 0.f;
        denom += p;
        acc = fmaf(p, xs, acc);
    }

    denom += __shfl_xor(denom, 8,  64);  acc += __shfl_xor(acc, 8,  64);
    denom += __shfl_xor(denom, 16, 64);  acc += __shfl_xor(acc, 16, 64);
    denom += __shfl_xor(denom, 32, 64);  acc += __shfl_xor(acc, 32, 64);

    if (sub == 0) out[d * OUT_DIM + c] = acc / denom + b2[c];
}

// ---------------- launch ----------------

extern "C" void kernel_launch(void* const* d_in, const int* in_sizes, int n_in,
                              void* d_out, int out_size, void* d_ws, size_t ws_size,
                              hipStream_t stream) {
    const float* x   = (const float*)d_in[0];
    const int*   ei  = (const int*)  d_in[1];
    const float* W1l = (const float*)d_in[2];
    const float* W1r = (const float*)d_in[3];
    const float* a1  = (const float*)d_in[4];
    const float* b1  = (const float*)d_in[5];
    const float* W2l = (const float*)d_in[6];
    const float* W2r = (const float*)d_in[7];
    const float* a2  = (const float*)d_in[8];
    const float* b2  = (const float*)d_in[9];
    float* out = (float*)d_out;

    char* ws = (char*)d_ws;
    size_t off = 0;
    auto carve = [&](size_t bytes) { char* p = ws + off; off += (bytes + 255) & ~size_t(255); return p; };
    int*    count     = (int*)   carve(N_NODES * sizeof(int));
    int*    row_start = (int*)   carve((N_NODES + 1) * sizeof(int));
    int*    cursor    = (int*)   carve(N_NODES * sizeof(int));
    int*    edge_src  = (int*)   carve(N_EDGE_T * sizeof(int));
    float*  xl2       = (float*) carve(N_NODES * OUT_DIM * sizeof(float));
    float*  xr2       = (float*) carve(N_NODES * OUT_DIM * sizeof(float));
    __half* xl_h      = (__half*)carve((size_t)N_NODES * 512 * sizeof(__half)); // 30.7MB

    proj_kernel   <<<1024, 256, 0, stream>>>(x, W1l, xl_h);
    zero_kernel   <<<(N_NODES  + 255) / 256, 256, 0, stream>>>(count);
    count_kernel  <<<(N_EDGE_T + 255) / 256, 256, 0, stream>>>(ei, count);
    scan_kernel   <<<1, 1024, 0, stream>>>(count, row_start, cursor);
    scatter_kernel<<<(N_EDGE_T + 255) / 256, 256, 0, stream>>>(ei, cursor, edge_src);
    layer1_kernel <<<N_NODES / 4, 256, 0, stream>>>(x, xl_h, W1r, a1, b1, W2l, W2r,
                                                    row_start, edge_src, xl2, xr2);
    layer2_kernel <<<(N_NODES + 3) / 4, 256, 0, stream>>>(xl2, xr2, a2, b2,
                                                          row_start, edge_src, out);
}

// Round 7
// 292.634 us; speedup vs baseline: 1.0490x; 1.0235x over previous
//
#include <hip/hip_runtime.h>
#include <hip/hip_fp16.h>
#include <math.h>

#define N_NODES   30000
#define N_EDGE    300000
#define N_EDGE_T  330000   // + self loops
#define HEADS     8
#define HIDDEN    64
#define IN_DIM    8
#define OUT_DIM   8
#define NEG_SLOPE 0.2f

// ---- DPP cross-lane reductions (pure VALU; no lgkmcnt) ----
#define DPP_ADDF(x, ctrl)                                                     \
    x += __int_as_float(__builtin_amdgcn_update_dpp(                          \
            0, __float_as_int(x), (ctrl), 0xF, 0xF, true))
// sum over aligned 16-lane group:
#define RED16(x) do { DPP_ADDF(x, 0xB1); DPP_ADDF(x, 0x4E);                   \
                      DPP_ADDF(x, 0x141); DPP_ADDF(x, 0x140); } while (0)
// sum over aligned 8-lane group:
#define RED8(x)  do { DPP_ADDF(x, 0xB1); DPP_ADDF(x, 0x4E);                   \
                      DPP_ADDF(x, 0x141); } while (0)

// ---------------- CSR build ----------------

__global__ __launch_bounds__(256) void zero_kernel(int* __restrict__ count) {
    int i = blockIdx.x * 256 + threadIdx.x;
    if (i < N_NODES) count[i] = 0;
}

__global__ __launch_bounds__(256) void count_kernel(const int* __restrict__ ei,
                                                    int* __restrict__ count) {
    int e = blockIdx.x * 256 + threadIdx.x;
    if (e >= N_EDGE_T) return;
    int d = (e < N_EDGE) ? ei[N_EDGE + e] : (e - N_EDGE);
    atomicAdd(&count[d], 1);
}

// Single-block scan, 8 ints/thread via 2x int4: 4 rounds.
__global__ __launch_bounds__(1024) void scan_kernel(const int* __restrict__ count,
                                                    int* __restrict__ row_start,
                                                    int* __restrict__ cursor) {
    __shared__ int wsum[16];
    const int tid  = threadIdx.x;
    const int wave = tid >> 6;
    const int lane = tid & 63;
    const int4* c4 = (const int4*)count;
    const int N4 = N_NODES / 4;              // 7500 int4s exactly
    int run = 0;
    for (int r = 0; r < 4; ++r) {
        const int g  = r * 1024 + tid;       // thread-slot in round
        const int i0 = 2 * g;                // int4 idx of first half
        const int i1 = 2 * g + 1;
        int4 v0 = make_int4(0,0,0,0), v1 = make_int4(0,0,0,0);
        if (i0 < N4) v0 = c4[i0];
        if (i1 < N4) v1 = c4[i1];
        int s = v0.x + v0.y + v0.z + v0.w + v1.x + v1.y + v1.z + v1.w;
        int sc = s;
        #pragma unroll
        for (int off = 1; off < 64; off <<= 1) {
            int t = __shfl_up(sc, off, 64);
            if (lane >= off) sc += t;
        }
        if (lane == 63) wsum[wave] = sc;
        __syncthreads();
        if (tid < 16) {
            int w = wsum[tid];
            #pragma unroll
            for (int off = 1; off < 16; off <<= 1) {
                int t = __shfl_up(w, off, 64);
                if (tid >= off) w += t;
            }
            wsum[tid] = w;
        }
        __syncthreads();
        const int woff = (wave > 0) ? wsum[wave - 1] : 0;
        int e0 = run + woff + (sc - s);       // exclusive prefix of this thread's 8
        int4 ex0, ex1;
        ex0.x = e0;           ex0.y = ex0.x + v0.x;
        ex0.z = ex0.y + v0.y; ex0.w = ex0.z + v0.z;
        int e4 = ex0.w + v0.w;
        ex1.x = e4;           ex1.y = ex1.x + v1.x;
        ex1.z = ex1.y + v1.y; ex1.w = ex1.z + v1.z;
        if (i0 < N4) { ((int4*)row_start)[i0] = ex0; ((int4*)cursor)[i0] = ex0; }
        if (i1 < N4) { ((int4*)row_start)[i1] = ex1; ((int4*)cursor)[i1] = ex1; }
        const int tot = wsum[15];
        __syncthreads();
        run += tot;
    }
    if (tid == 0) row_start[N_NODES] = run;
}

__global__ __launch_bounds__(256) void scatter_kernel(const int* __restrict__ ei,
                                                      int* __restrict__ cursor,
                                                      int* __restrict__ edge_src) {
    int e = blockIdx.x * 256 + threadIdx.x;
    if (e >= N_EDGE_T) return;
    int s, d;
    if (e < N_EDGE) { s = ei[e]; d = ei[N_EDGE + e]; }
    else            { s = d = e - N_EDGE; }
    int pos = atomicAdd(&cursor[d], 1);
    edge_src[pos] = s;
}

// ---------------- Projection precompute (fp16) ----------------
// xl = x @ W1l once per node, packed half2: 1KB/row, 30.7MB table.
// R7: x row via per-lane VMEM + shfl broadcast (was 8 wave-uniform s_loads
// per node -> ~1M K$ misses across the kernel; K$-contention theory).

__global__ __launch_bounds__(256) void proj_kernel(
    const float* __restrict__ x, const float* __restrict__ W1l,
    __half* __restrict__ xl_h)
{
    const int t    = threadIdx.x;        // col pair (2t, 2t+1)
    const int lane = t & 63;
    float w0[IN_DIM], w1[IN_DIM];
    #pragma unroll
    for (int k = 0; k < IN_DIM; ++k) {
        const float2 wp = *(const float2*)&W1l[k * 512 + 2 * t];
        w0[k] = wp.x; w1[k] = wp.y;
    }
    for (int n = blockIdx.x; n < N_NODES; n += gridDim.x) {
        const float xlane = x[n * IN_DIM + (lane & 7)];   // VMEM, coalesced
        float l0 = 0.f, l1 = 0.f;
        #pragma unroll
        for (int k = 0; k < IN_DIM; ++k) {
            const float xk = __shfl(xlane, k, 64);
            l0 = fmaf(xk, w0[k], l0);
            l1 = fmaf(xk, w1[k], l1);
        }
        ((__half2*)xl_h)[n * 256 + t] = __floats2half2_rn(l0, l1);
    }
}

// ---------------- Layer 1 (R7: zero scalar-memory) ----------------
// 1 wave = 1 node (R6 structure) with every wave-uniform load converted to
// per-lane VMEM + shfl:
//   row_start  -> row_start[d+(lane&1)] + 2 shfl
//   edge list  -> ONE coalesced batch load (deg<=64 w.h.p.) into a register;
//                 per-edge index = __shfl(eidx, j): register traffic only
//   x[d] row   -> per-lane load + 8 shfl broadcasts
// With indices register-resident the gather stream has no load->load dep:
// 4-deep explicit prefetch + sched_barrier(0) so issues stay above compute.

__global__ void __launch_bounds__(256, 4)
layer1_kernel(
    const float* __restrict__ x,
    const __half* __restrict__ xl_h, const float* __restrict__ W1r,
    const float* __restrict__ a1,  const float* __restrict__ b1,
    const float* __restrict__ W2l, const float* __restrict__ W2r,
    const int* __restrict__ row_start, const int* __restrict__ edge_src,
    float* __restrict__ xl2, float* __restrict__ xr2)
{
    const int wv   = threadIdx.x >> 6;     // 0..3
    const int lane = threadIdx.x & 63;
    const int d    = blockIdx.x * 4 + wv;  // 30000 = 7500*4 exactly
    const int colb = lane * 8;             // 8 contiguous columns per lane

    // per-node metadata — all VMEM
    const int rse = row_start[d + (lane & 1)];
    const int rs  = __shfl(rse, 0, 64);
    const int re  = __shfl(rse, 1, 64);
    const int deg = re - rs;
    const int nb  = deg < 64 ? deg : 64;

    const int eidx = edge_src[rs + (lane < deg ? lane : deg - 1)]; // batch

    const float xlane = x[d * IN_DIM + (lane & 7)];

    float av[8], xr[8];
    { const float4 a0 = *(const float4*)&a1[colb];
      const float4 a4 = *(const float4*)&a1[colb + 4];
      av[0]=a0.x; av[1]=a0.y; av[2]=a0.z; av[3]=a0.w;
      av[4]=a4.x; av[5]=a4.y; av[6]=a4.z; av[7]=a4.w; }
    #pragma unroll
    for (int i = 0; i < 8; ++i) xr[i] = 0.f;
    #pragma unroll
    for (int k = 0; k < IN_DIM; ++k) {
        const float xv = __shfl(xlane, k, 64);
        const float4 r0 = *(const float4*)&W1r[k * 512 + colb];
        const float4 r4 = *(const float4*)&W1r[k * 512 + colb + 4];
        xr[0] = fmaf(xv, r0.x, xr[0]); xr[1] = fmaf(xv, r0.y, xr[1]);
        xr[2] = fmaf(xv, r0.z, xr[2]); xr[3] = fmaf(xv, r0.w, xr[3]);
        xr[4] = fmaf(xv, r4.x, xr[4]); xr[5] = fmaf(xv, r4.y, xr[5]);
        xr[6] = fmaf(xv, r4.z, xr[6]); xr[7] = fmaf(xv, r4.w, xr[7]);
    }

    float denom  = 0.f;
    float acc[8] = {0.f,0.f,0.f,0.f,0.f,0.f,0.f,0.f};

    // slot j (< nb) -> 16B row-fragment load; index from register batch
    auto ldraw = [&](int j) -> int4 {
        const int s = __shfl(eidx, j, 64);
        return *(const int4*)(xl_h + (size_t)s * 512 + colb);
    };
    auto edge1 = [&](const int4 r, bool valid) {
        union { int i; __half2 h; } u0, u1, u2, u3;
        u0.i = r.x; u1.i = r.y; u2.i = r.z; u3.i = r.w;
        float rr[8]; float2 f;
        f = __half22float2(u0.h); rr[0] = f.x; rr[1] = f.y;
        f = __half22float2(u1.h); rr[2] = f.x; rr[3] = f.y;
        f = __half22float2(u2.h); rr[4] = f.x; rr[5] = f.y;
        f = __half22float2(u3.h); rr[6] = f.x; rr[7] = f.y;
        float e = 0.f;
        #pragma unroll
        for (int i = 0; i < 8; ++i) {
            const float q = rr[i] + xr[i];
            const float t = fmaxf(q, NEG_SLOPE * q);
            e = fmaf(av[i], t, e);
        }
        RED8(e);                               // head group = 8 lanes
        const float p = valid ? __expf(e) : 0.f;
        denom += p;
        #pragma unroll
        for (int i = 0; i < 8; ++i) acc[i] = fmaf(p, rr[i], acc[i]);
    };

    // 4-deep pipeline over slots [0, nb)
    int4 R0, R1, R2, R3;
    {
        const int m = nb - 1;
        R0 = ldraw(0);
        R1 = ldraw(1 < m ? 1 : m);
        R2 = ldraw(2 < m ? 2 : m);
        R3 = ldraw(3 < m ? 3 : m);
    }
    for (int j = 0;; j += 4) {
        const bool more = j + 4 < nb;
        int4 N0, N1, N2, N3;
        if (more) {
            const int m = nb - 1;
            const int j4 = j + 4;
            N0 = ldraw(j4 < m ? j4 : m);
            N1 = ldraw(j4 + 1 < m ? j4 + 1 : m);
            N2 = ldraw(j4 + 2 < m ? j4 + 2 : m);
            N3 = ldraw(j4 + 3 < m ? j4 + 3 : m);
            __builtin_amdgcn_sched_barrier(0);   // keep issues above compute
        }
        edge1(R0, true);            // j < nb always (nb >= 1)
        edge1(R1, j + 1 < nb);
        edge1(R2, j + 2 < nb);
        edge1(R3, j + 3 < nb);
        if (!more) break;
        R0 = N0; R1 = N1; R2 = N2; R3 = N3;
    }
    // pathological tail (deg > 64): effectively never for Poisson(11)
    for (int j = 64; j < deg; ++j) {
        const int s = edge_src[rs + j];
        const int4 r = *(const int4*)(xl_h + (size_t)s * 512 + colb);
        edge1(r, true);
    }

    // h = relu(acc/denom + b1)
    const float inv = 1.f / denom;
    float hv[8];
    { const float4 b0 = *(const float4*)&b1[colb];
      const float4 b4 = *(const float4*)&b1[colb + 4];
      hv[0] = fmaxf(fmaf(acc[0], inv, b0.x), 0.f);
      hv[1] = fmaxf(fmaf(acc[1], inv, b0.y), 0.f);
      hv[2] = fmaxf(fmaf(acc[2], inv, b0.z), 0.f);
      hv[3] = fmaxf(fmaf(acc[3], inv, b0.w), 0.f);
      hv[4] = fmaxf(fmaf(acc[4], inv, b4.x), 0.f);
      hv[5] = fmaxf(fmaf(acc[5], inv, b4.y), 0.f);
      hv[6] = fmaxf(fmaf(acc[6], inv, b4.z), 0.f);
      hv[7] = fmaxf(fmaf(acc[7], inv, b4.w), 0.f); }

    // Epilogue: h @ W2{l,r} entirely in-wave (no LDS, no barrier).
    float vl[OUT_DIM], vr[OUT_DIM];
    #pragma unroll
    for (int j = 0; j < OUT_DIM; ++j) { vl[j] = 0.f; vr[j] = 0.f; }
    #pragma unroll
    for (int i = 0; i < 8; ++i) {
        const int c = colb + i;
        const float4 l0 = *(const float4*)&W2l[c * OUT_DIM];
        const float4 l1 = *(const float4*)&W2l[c * OUT_DIM + 4];
        const float4 r0 = *(const float4*)&W2r[c * OUT_DIM];
        const float4 r1 = *(const float4*)&W2r[c * OUT_DIM + 4];
        const float h = hv[i];
        vl[0] = fmaf(h, l0.x, vl[0]); vl[1] = fmaf(h, l0.y, vl[1]);
        vl[2] = fmaf(h, l0.z, vl[2]); vl[3] = fmaf(h, l0.w, vl[3]);
        vl[4] = fmaf(h, l1.x, vl[4]); vl[5] = fmaf(h, l1.y, vl[5]);
        vl[6] = fmaf(h, l1.z, vl[6]); vl[7] = fmaf(h, l1.w, vl[7]);
        vr[0] = fmaf(h, r0.x, vr[0]); vr[1] = fmaf(h, r0.y, vr[1]);
        vr[2] = fmaf(h, r0.z, vr[2]); vr[3] = fmaf(h, r0.w, vr[3]);
        vr[4] = fmaf(h, r1.x, vr[4]); vr[5] = fmaf(h, r1.y, vr[5]);
        vr[6] = fmaf(h, r1.z, vr[6]); vr[7] = fmaf(h, r1.w, vr[7]);
    }
    #pragma unroll
    for (int j = 0; j < OUT_DIM; ++j) {
        RED16(vl[j]);
        vl[j] += __shfl_xor(vl[j], 16, 64);
        vl[j] += __shfl_xor(vl[j], 32, 64);
        RED16(vr[j]);
        vr[j] += __shfl_xor(vr[j], 16, 64);
        vr[j] += __shfl_xor(vr[j], 32, 64);
    }
    if (lane == 0) {
        *(float4*)&xl2[d * OUT_DIM]     = make_float4(vl[0], vl[1], vl[2], vl[3]);
        *(float4*)&xl2[d * OUT_DIM + 4] = make_float4(vl[4], vl[5], vl[6], vl[7]);
        *(float4*)&xr2[d * OUT_DIM]     = make_float4(vr[0], vr[1], vr[2], vr[3]);
        *(float4*)&xr2[d * OUT_DIM + 4] = make_float4(vr[4], vr[5], vr[6], vr[7]);
    }
}

// ---------------- Layer 2 (1 head, dim 8) ----------------
// R7: row_start via per-lane VMEM + shfl (was 2 s_loads/wave); everything
// else already on the vector path. Common case (deg<=16) straight-line.

__global__ __launch_bounds__(256) void layer2_kernel(
    const float* __restrict__ xl2, const float* __restrict__ xr2,
    const float* __restrict__ a2,  const float* __restrict__ b2,
    const int* __restrict__ row_start, const int* __restrict__ edge_src,
    float* __restrict__ out)
{
    const int wave = threadIdx.x >> 6;
    const int lane = threadIdx.x & 63;
    const int d = blockIdx.x * 4 + wave;
    if (d >= N_NODES) return;
    const int sub = lane >> 3;   // edge slot 0..7
    const int c   = lane & 7;    // channel

    const int rse = row_start[d + (lane & 1)];   // VMEM
    const int rs  = __shfl(rse, 0, 64);
    const int re  = __shfl(rse, 1, 64);

    const float a_c  = a2[c];
    const float xr_d = xr2[d * OUT_DIM + c];

    // groups 0 and 1 upfront, loads in flight together
    int  e0 = rs + sub;      const bool v0 = e0 < re; e0 = v0 ? e0 : re - 1;
    int  e1 = rs + 8 + sub;  const bool v1 = e1 < re; e1 = v1 ? e1 : re - 1;
    const int s0 = edge_src[e0];
    const int s1 = edge_src[e1];
    const float x0 = xl2[s0 * OUT_DIM + c];
    const float x1 = xl2[s1 * OUT_DIM + c];

    const float u0 = x0 + xr_d; const float t0 = fmaxf(u0, NEG_SLOPE * u0);
    const float u1 = x1 + xr_d; const float t1 = fmaxf(u1, NEG_SLOPE * u1);
    float g0 = a_c * t0;
    float g1 = a_c * t1;
    RED8(g0); RED8(g1);                      // independent DPP chains
    const float p0 = v0 ? __expf(g0) : 0.f;
    const float p1 = v1 ? __expf(g1) : 0.f;
    float denom = p0 + p1;
    float acc   = fmaf(p1, x1, p0 * x0);

    // rare tail: deg > 16
    for (int b = rs + 16; b < re; b += 8) {
        int e = b + sub;
        const bool v = e < re; e = v ? e : re - 1;
        const int s = edge_src[e];
        const float xs = xl2[s * OUT_DIM + c];
        const float u = xs + xr_d;
        const float t = fmaxf(u, NEG_SLOPE * u);
        float g = a_c * t;
        RED8(g);
        const float p = v ? __expf(g) : 0.f;
        denom += p;
        acc = fmaf(p, xs, acc);
    }

    denom += __shfl_xor(denom, 8,  64);  acc += __shfl_xor(acc, 8,  64);
    denom += __shfl_xor(denom, 16, 64);  acc += __shfl_xor(acc, 16, 64);
    denom += __shfl_xor(denom, 32, 64);  acc += __shfl_xor(acc, 32, 64);

    if (sub == 0) out[d * OUT_DIM + c] = acc / denom + b2[c];
}

// ---------------- launch ----------------

extern "C" void kernel_launch(void* const* d_in, const int* in_sizes, int n_in,
                              void* d_out, int out_size, void* d_ws, size_t ws_size,
                              hipStream_t stream) {
    const float* x   = (const float*)d_in[0];
    const int*   ei  = (const int*)  d_in[1];
    const float* W1l = (const float*)d_in[2];
    const float* W1r = (const float*)d_in[3];
    const float* a1  = (const float*)d_in[4];
    const float* b1  = (const float*)d_in[5];
    const float* W2l = (const float*)d_in[6];
    const float* W2r = (const float*)d_in[7];
    const float* a2  = (const float*)d_in[8];
    const float* b2  = (const float*)d_in[9];
    float* out = (float*)d_out;

    char* ws = (char*)d_ws;
    size_t off = 0;
    auto carve = [&](size_t bytes) { char* p = ws + off; off += (bytes + 255) & ~size_t(255); return p; };
    int*    count     = (int*)   carve(N_NODES * sizeof(int));
    int*    row_start = (int*)   carve((N_NODES + 1) * sizeof(int));
    int*    cursor    = (int*)   carve(N_NODES * sizeof(int));
    int*    edge_src  = (int*)   carve(N_EDGE_T * sizeof(int));
    float*  xl2       = (float*) carve(N_NODES * OUT_DIM * sizeof(float));
    float*  xr2       = (float*) carve(N_NODES * OUT_DIM * sizeof(float));
    __half* xl_h      = (__half*)carve((size_t)N_NODES * 512 * sizeof(__half)); // 30.7MB

    proj_kernel   <<<1024, 256, 0, stream>>>(x, W1l, xl_h);
    zero_kernel   <<<(N_NODES  + 255) / 256, 256, 0, stream>>>(count);
    count_kernel  <<<(N_EDGE_T + 255) / 256, 256, 0, stream>>>(ei, count);
    scan_kernel   <<<1, 1024, 0, stream>>>(count, row_start, cursor);
    scatter_kernel<<<(N_EDGE_T + 255) / 256, 256, 0, stream>>>(ei, cursor, edge_src);
    layer1_kernel <<<N_NODES / 4, 256, 0, stream>>>(x, xl_h, W1r, a1, b1, W2l, W2r,
                                                    row_start, edge_src, xl2, xr2);
    layer2_kernel <<<(N_NODES + 3) / 4, 256, 0, stream>>>(xl2, xr2, a2, b2,
                                                          row_start, edge_src, out);
}

// Round 10
// 266.212 us; speedup vs baseline: 1.1531x; 1.0993x over previous
//
#include <hip/hip_runtime.h>
#include <math.h>

#define N_NODES   30000
#define N_EDGE    300000
#define N_EDGE_T  330000   // + self loops
#define HEADS     8
#define HIDDEN    64
#define IN_DIM    8
#define OUT_DIM   8
#define NEG_SLOPE 0.2f

#define PIN_V(v) asm volatile("" : "+v"(v))

// ---- DPP cross-lane reductions (pure VALU; no lgkmcnt) ----
#define DPP_ADDF(x, ctrl)                                                     \
    x += __int_as_float(__builtin_amdgcn_update_dpp(                          \
            0, __float_as_int(x), (ctrl), 0xF, 0xF, true))
// sum over aligned 16-lane group:
#define RED16(x) do { DPP_ADDF(x, 0xB1); DPP_ADDF(x, 0x4E);                   \
                      DPP_ADDF(x, 0x141); DPP_ADDF(x, 0x140); } while (0)
// sum over aligned 8-lane group:
#define RED8(x)  do { DPP_ADDF(x, 0xB1); DPP_ADDF(x, 0x4E);                   \
                      DPP_ADDF(x, 0x141); } while (0)

// broadcast lane C (compile-time) -> SGPR; VALU-only, no DS/lgkm
#define BCAST(v, C) __int_as_float(__builtin_amdgcn_readlane(__float_as_int(v), C))

// ---------------- CSR build ----------------

__global__ __launch_bounds__(256) void zero_kernel(int* __restrict__ count) {
    int i = blockIdx.x * 256 + threadIdx.x;
    if (i < N_NODES) count[i] = 0;
}

__global__ __launch_bounds__(256) void count_kernel(const int* __restrict__ ei,
                                                    int* __restrict__ count) {
    int e = blockIdx.x * 256 + threadIdx.x;
    if (e >= N_EDGE_T) return;
    int d = (e < N_EDGE) ? ei[N_EDGE + e] : (e - N_EDGE);
    atomicAdd(&count[d], 1);
}

// Single-block scan, 8 ints/thread via 2x int4: 4 rounds.
__global__ __launch_bounds__(1024) void scan_kernel(const int* __restrict__ count,
                                                    int* __restrict__ row_start,
                                                    int* __restrict__ cursor) {
    __shared__ int wsum[16];
    const int tid  = threadIdx.x;
    const int wave = tid >> 6;
    const int lane = tid & 63;
    const int4* c4 = (const int4*)count;
    const int N4 = N_NODES / 4;              // 7500 int4s exactly
    int run = 0;
    for (int r = 0; r < 4; ++r) {
        const int g  = r * 1024 + tid;       // thread-slot in round
        const int i0 = 2 * g;                // int4 idx of first half
        const int i1 = 2 * g + 1;
        int4 v0 = make_int4(0,0,0,0), v1 = make_int4(0,0,0,0);
        if (i0 < N4) v0 = c4[i0];
        if (i1 < N4) v1 = c4[i1];
        int s = v0.x + v0.y + v0.z + v0.w + v1.x + v1.y + v1.z + v1.w;
        int sc = s;
        #pragma unroll
        for (int off = 1; off < 64; off <<= 1) {
            int t = __shfl_up(sc, off, 64);
            if (lane >= off) sc += t;
        }
        if (lane == 63) wsum[wave] = sc;
        __syncthreads();
        if (tid < 16) {
            int w = wsum[tid];
            #pragma unroll
            for (int off = 1; off < 16; off <<= 1) {
                int t = __shfl_up(w, off, 64);
                if (tid >= off) w += t;
            }
            wsum[tid] = w;
        }
        __syncthreads();
        const int woff = (wave > 0) ? wsum[wave - 1] : 0;
        int e0 = run + woff + (sc - s);       // exclusive prefix of this thread's 8
        int4 ex0, ex1;
        ex0.x = e0;           ex0.y = ex0.x + v0.x;
        ex0.z = ex0.y + v0.y; ex0.w = ex0.z + v0.z;
        int e4 = ex0.w + v0.w;
        ex1.x = e4;           ex1.y = ex1.x + v1.x;
        ex1.z = ex1.y + v1.y; ex1.w = ex1.z + v1.z;
        if (i0 < N4) { ((int4*)row_start)[i0] = ex0; ((int4*)cursor)[i0] = ex0; }
        if (i1 < N4) { ((int4*)row_start)[i1] = ex1; ((int4*)cursor)[i1] = ex1; }
        const int tot = wsum[15];
        __syncthreads();
        run += tot;
    }
    if (tid == 0) row_start[N_NODES] = run;
}

__global__ __launch_bounds__(256) void scatter_kernel(const int* __restrict__ ei,
                                                      int* __restrict__ cursor,
                                                      int* __restrict__ edge_src) {
    int e = blockIdx.x * 256 + threadIdx.x;
    if (e >= N_EDGE_T) return;
    int s, d;
    if (e < N_EDGE) { s = ei[e]; d = ei[N_EDGE + e]; }
    else            { s = d = e - N_EDGE; }
    int pos = atomicAdd(&cursor[d], 1);
    edge_src[pos] = s;
}

// ---------------- Layer 1 (recompute, not gather) ----------------
// R7 post-mortem: the 1KB/edge table gather (338MB, random, >L2 working set)
// is Little's-law-bound at ~1 TB/s effective -> 160us floor across 5
// structures. This kernel eliminates the table: xl[src] is recomputed per
// edge from x[src] (32B/edge -> 21MB total, L2-resident) with W1l PINNED in
// registers (8 cols/lane x 8 k = 64 VGPR). Per 8-edge group: ONE coalesced
// x gather (8 lanes/edge, 8 lines/instr) prefetched one group (~1800cy)
// ahead; v_readlane (const lane, VALU-only) broadcasts x values; q-space
// softmax accumulation (acc' = sum p*(xl+xr); out = acc'/denom - xr).
// fp32 exact everywhere. Target: VALU-bound (~2.7 GFLOP total).
// (Benches R8/R9 never ran: container acquisition failed both times —
// no timing block, vs R4/R5 kernel-crashes which had full timing+traceback.
// Source audited twice; resubmitted unchanged.)

__global__ void __launch_bounds__(256, 4)
layer1_kernel(
    const float* __restrict__ x,
    const float* __restrict__ W1l, const float* __restrict__ W1r,
    const float* __restrict__ a1,  const float* __restrict__ b1,
    const float* __restrict__ W2l, const float* __restrict__ W2r,
    const int* __restrict__ row_start, const int* __restrict__ edge_src,
    float* __restrict__ xl2, float* __restrict__ xr2)
{
    const int wv   = threadIdx.x >> 6;     // 0..3
    const int lane = threadIdx.x & 63;
    const int d    = blockIdx.x * 4 + wv;  // 30000 = 7500*4 exactly
    const int colb = lane * 8;             // 8 contiguous columns per lane

    // per-node metadata — all VMEM (R7: no scalar loads in hot paths)
    const int rse = row_start[d + (lane & 1)];
    const int rs  = __shfl(rse, 0, 64);
    const int re  = __shfl(rse, 1, 64);
    const int deg = re - rs;
    const int nb  = deg < 64 ? deg : 64;

    // register-resident edge batch: lane l holds edge_src[rs + min(l,deg-1)]
    const int eidx = edge_src[rs + (lane < deg ? lane : deg - 1)];

    // x[d] row: per-lane VMEM; lanes 0..7 hold x[d][0..7] (replicated /8)
    const float xd = x[d * IN_DIM + (lane & 7)];

    // W1l fragment: 8 cols x 8 k per lane, pinned
    float wl[IN_DIM][8];
    #pragma unroll
    for (int k = 0; k < IN_DIM; ++k) {
        const float4 l0 = *(const float4*)&W1l[k * 512 + colb];
        const float4 l4 = *(const float4*)&W1l[k * 512 + colb + 4];
        wl[k][0] = l0.x; wl[k][1] = l0.y; wl[k][2] = l0.z; wl[k][3] = l0.w;
        wl[k][4] = l4.x; wl[k][5] = l4.y; wl[k][6] = l4.z; wl[k][7] = l4.w;
    }
    float av[8];
    { const float4 a0 = *(const float4*)&a1[colb];
      const float4 a4 = *(const float4*)&a1[colb + 4];
      av[0]=a0.x; av[1]=a0.y; av[2]=a0.z; av[3]=a0.w;
      av[4]=a4.x; av[5]=a4.y; av[6]=a4.z; av[7]=a4.w; }

    // xr via W1r (streamed, L2-hot) and readlane broadcasts of xd
    float xr[8];
    #pragma unroll
    for (int i = 0; i < 8; ++i) xr[i] = 0.f;
    #pragma unroll
    for (int k = 0; k < IN_DIM; ++k) {
        const float xv = BCAST(xd, k);
        const float4 r0 = *(const float4*)&W1r[k * 512 + colb];
        const float4 r4 = *(const float4*)&W1r[k * 512 + colb + 4];
        xr[0] = fmaf(xv, r0.x, xr[0]); xr[1] = fmaf(xv, r0.y, xr[1]);
        xr[2] = fmaf(xv, r0.z, xr[2]); xr[3] = fmaf(xv, r0.w, xr[3]);
        xr[4] = fmaf(xv, r4.x, xr[4]); xr[5] = fmaf(xv, r4.y, xr[5]);
        xr[6] = fmaf(xv, r4.z, xr[6]); xr[7] = fmaf(xv, r4.w, xr[7]);
    }

    #pragma unroll
    for (int k = 0; k < IN_DIM; ++k) {
        #pragma unroll
        for (int i = 0; i < 8; ++i) PIN_V(wl[k][i]);
    }
    #pragma unroll
    for (int i = 0; i < 8; ++i) { PIN_V(av[i]); PIN_V(xr[i]); }

    float denom  = 0.f;
    float acc[8] = {0.f,0.f,0.f,0.f,0.f,0.f,0.f,0.f};  // q-space: sum p*(xl+xr)

    // group-g x gather: lane l -> x[src(edge 8g+(l>>3))][l&7]; 8 lines/instr
    auto ldx = [&](int g) -> float {
        const int sl = __shfl(eidx, (g << 3) + (lane >> 3), 64);
        return x[(size_t)sl * IN_DIM + (lane & 7)];
    };

    // process one edge: x values come from readlane of the group vector
    auto edge_do = [&](float q0, float q1, float q2, float q3,
                       float q4, float q5, float q6, float q7, bool valid) {
        float t, e;
        t = fmaxf(q0, NEG_SLOPE * q0); e = av[0] * t;
        t = fmaxf(q1, NEG_SLOPE * q1); e = fmaf(av[1], t, e);
        t = fmaxf(q2, NEG_SLOPE * q2); e = fmaf(av[2], t, e);
        t = fmaxf(q3, NEG_SLOPE * q3); e = fmaf(av[3], t, e);
        t = fmaxf(q4, NEG_SLOPE * q4); e = fmaf(av[4], t, e);
        t = fmaxf(q5, NEG_SLOPE * q5); e = fmaf(av[5], t, e);
        t = fmaxf(q6, NEG_SLOPE * q6); e = fmaf(av[6], t, e);
        t = fmaxf(q7, NEG_SLOPE * q7); e = fmaf(av[7], t, e);
        RED8(e);                              // head group = 8 lanes
        const float p = valid ? __expf(e) : 0.f;
        denom += p;
        acc[0] = fmaf(p, q0, acc[0]); acc[1] = fmaf(p, q1, acc[1]);
        acc[2] = fmaf(p, q2, acc[2]); acc[3] = fmaf(p, q3, acc[3]);
        acc[4] = fmaf(p, q4, acc[4]); acc[5] = fmaf(p, q5, acc[5]);
        acc[6] = fmaf(p, q6, acc[6]); acc[7] = fmaf(p, q7, acc[7]);
    };

    float xg = ldx(0);
    for (int g = 0;; ++g) {
        const bool more = ((g + 1) << 3) < nb;
        float xgn;
        if (more) xgn = ldx(g + 1);           // prefetch: ~1800cy of cover

        #pragma unroll
        for (int jj = 0; jj < 8; ++jj) {
            const int j = (g << 3) + jj;
            // q_i = xr_i + sum_k x_k * wl[k][i]  (x_k uniform via readlane)
            float q0 = xr[0], q1 = xr[1], q2 = xr[2], q3 = xr[3];
            float q4 = xr[4], q5 = xr[5], q6 = xr[6], q7 = xr[7];
            #pragma unroll
            for (int k = 0; k < IN_DIM; ++k) {
                const float xk = BCAST(xg, jj * 8 + k);
                q0 = fmaf(xk, wl[k][0], q0); q1 = fmaf(xk, wl[k][1], q1);
                q2 = fmaf(xk, wl[k][2], q2); q3 = fmaf(xk, wl[k][3], q3);
                q4 = fmaf(xk, wl[k][4], q4); q5 = fmaf(xk, wl[k][5], q5);
                q6 = fmaf(xk, wl[k][6], q6); q7 = fmaf(xk, wl[k][7], q7);
            }
            edge_do(q0, q1, q2, q3, q4, q5, q6, q7, j < nb);
        }
        if (!more) break;
        xg = xgn;
    }
    // pathological tail (deg > 64): effectively never for Poisson(11)
    for (int j = 64; j < deg; ++j) {
        const int s = edge_src[rs + j];
        const float xt = x[(size_t)s * IN_DIM + (lane & 7)];
        float q0 = xr[0], q1 = xr[1], q2 = xr[2], q3 = xr[3];
        float q4 = xr[4], q5 = xr[5], q6 = xr[6], q7 = xr[7];
        #pragma unroll
        for (int k = 0; k < IN_DIM; ++k) {
            const float xk = BCAST(xt, k);
            q0 = fmaf(xk, wl[k][0], q0); q1 = fmaf(xk, wl[k][1], q1);
            q2 = fmaf(xk, wl[k][2], q2); q3 = fmaf(xk, wl[k][3], q3);
            q4 = fmaf(xk, wl[k][4], q4); q5 = fmaf(xk, wl[k][5], q5);
            q6 = fmaf(xk, wl[k][6], q6); q7 = fmaf(xk, wl[k][7], q7);
        }
        edge_do(q0, q1, q2, q3, q4, q5, q6, q7, true);
    }

    // h = relu(acc/denom - xr + b1)   (q-space -> xl-space)
    const float inv = 1.f / denom;
    float hv[8];
    { const float4 b0 = *(const float4*)&b1[colb];
      const float4 b4 = *(const float4*)&b1[colb + 4];
      hv[0] = fmaxf(fmaf(acc[0], inv, b0.x - xr[0]), 0.f);
      hv[1] = fmaxf(fmaf(acc[1], inv, b0.y - xr[1]), 0.f);
      hv[2] = fmaxf(fmaf(acc[2], inv, b0.z - xr[2]), 0.f);
      hv[3] = fmaxf(fmaf(acc[3], inv, b0.w - xr[3]), 0.f);
      hv[4] = fmaxf(fmaf(acc[4], inv, b4.x - xr[4]), 0.f);
      hv[5] = fmaxf(fmaf(acc[5], inv, b4.y - xr[5]), 0.f);
      hv[6] = fmaxf(fmaf(acc[6], inv, b4.z - xr[6]), 0.f);
      hv[7] = fmaxf(fmaf(acc[7], inv, b4.w - xr[7]), 0.f); }

    // Epilogue: h @ W2{l,r} entirely in-wave (no LDS, no barrier).
    float vl[OUT_DIM], vr[OUT_DIM];
    #pragma unroll
    for (int j = 0; j < OUT_DIM; ++j) { vl[j] = 0.f; vr[j] = 0.f; }
    #pragma unroll
    for (int i = 0; i < 8; ++i) {
        const int c = colb + i;
        const float4 l0 = *(const float4*)&W2l[c * OUT_DIM];
        const float4 l1 = *(const float4*)&W2l[c * OUT_DIM + 4];
        const float4 r0 = *(const float4*)&W2r[c * OUT_DIM];
        const float4 r1 = *(const float4*)&W2r[c * OUT_DIM + 4];
        const float h = hv[i];
        vl[0] = fmaf(h, l0.x, vl[0]); vl[1] = fmaf(h, l0.y, vl[1]);
        vl[2] = fmaf(h, l0.z, vl[2]); vl[3] = fmaf(h, l0.w, vl[3]);
        vl[4] = fmaf(h, l1.x, vl[4]); vl[5] = fmaf(h, l1.y, vl[5]);
        vl[6] = fmaf(h, l1.z, vl[6]); vl[7] = fmaf(h, l1.w, vl[7]);
        vr[0] = fmaf(h, r0.x, vr[0]); vr[1] = fmaf(h, r0.y, vr[1]);
        vr[2] = fmaf(h, r0.z, vr[2]); vr[3] = fmaf(h, r0.w, vr[3]);
        vr[4] = fmaf(h, r1.x, vr[4]); vr[5] = fmaf(h, r1.y, vr[5]);
        vr[6] = fmaf(h, r1.z, vr[6]); vr[7] = fmaf(h, r1.w, vr[7]);
    }
    #pragma unroll
    for (int j = 0; j < OUT_DIM; ++j) {
        RED16(vl[j]);
        vl[j] += __shfl_xor(vl[j], 16, 64);
        vl[j] += __shfl_xor(vl[j], 32, 64);
        RED16(vr[j]);
        vr[j] += __shfl_xor(vr[j], 16, 64);
        vr[j] += __shfl_xor(vr[j], 32, 64);
    }
    if (lane == 0) {
        *(float4*)&xl2[d * OUT_DIM]     = make_float4(vl[0], vl[1], vl[2], vl[3]);
        *(float4*)&xl2[d * OUT_DIM + 4] = make_float4(vl[4], vl[5], vl[6], vl[7]);
        *(float4*)&xr2[d * OUT_DIM]     = make_float4(vr[0], vr[1], vr[2], vr[3]);
        *(float4*)&xr2[d * OUT_DIM + 4] = make_float4(vr[4], vr[5], vr[6], vr[7]);
    }
}

// ---------------- Layer 2 (1 head, dim 8) ----------------
// Common case (deg<=16, ~94% of Poisson-11 nodes) straight-line; tail loops.

__global__ __launch_bounds__(256) void layer2_kernel(
    const float* __restrict__ xl2, const float* __restrict__ xr2,
    const float* __restrict__ a2,  const float* __restrict__ b2,
    const int* __restrict__ row_start, const int* __restrict__ edge_src,
    float* __restrict__ out)
{
    const int wave = threadIdx.x >> 6;
    const int lane = threadIdx.x & 63;
    const int d = blockIdx.x * 4 + wave;
    if (d >= N_NODES) return;
    const int sub = lane >> 3;   // edge slot 0..7
    const int c   = lane & 7;    // channel

    const int rse = row_start[d + (lane & 1)];   // VMEM
    const int rs  = __shfl(rse, 0, 64);
    const int re  = __shfl(rse, 1, 64);

    const float a_c  = a2[c];
    const float xr_d = xr2[d * OUT_DIM + c];

    // groups 0 and 1 upfront, loads in flight together
    int  e0 = rs + sub;      const bool v0 = e0 < re; e0 = v0 ? e0 : re - 1;
    int  e1 = rs + 8 + sub;  const bool v1 = e1 < re; e1 = v1 ? e1 : re - 1;
    const int s0 = edge_src[e0];
    const int s1 = edge_src[e1];
    const float x0 = xl2[s0 * OUT_DIM + c];
    const float x1 = xl2[s1 * OUT_DIM + c];

    const float u0 = x0 + xr_d; const float t0 = fmaxf(u0, NEG_SLOPE * u0);
    const float u1 = x1 + xr_d; const float t1 = fmaxf(u1, NEG_SLOPE * u1);
    float g0 = a_c * t0;
    float g1 = a_c * t1;
    RED8(g0); RED8(g1);                      // independent DPP chains
    const float p0 = v0 ? __expf(g0) : 0.f;
    const float p1 = v1 ? __expf(g1) : 0.f;
    float denom = p0 + p1;
    float acc   = fmaf(p1, x1, p0 * x0);

    // rare tail: deg > 16
    for (int b = rs + 16; b < re; b += 8) {
        int e = b + sub;
        const bool v = e < re; e = v ? e : re - 1;
        const int s = edge_src[e];
        const float xs = xl2[s * OUT_DIM + c];
        const float u = xs + xr_d;
        const float t = fmaxf(u, NEG_SLOPE * u);
        float g = a_c * t;
        RED8(g);
        const float p = v ? __expf(g) : 0.f;
        denom += p;
        acc = fmaf(p, xs, acc);
    }

    denom += __shfl_xor(denom, 8,  64);  acc += __shfl_xor(acc, 8,  64);
    denom += __shfl_xor(denom, 16, 64);  acc += __shfl_xor(acc, 16, 64);
    denom += __shfl_xor(denom, 32, 64);  acc += __shfl_xor(acc, 32, 64);

    if (sub == 0) out[d * OUT_DIM + c] = acc / denom + b2[c];
}

// ---------------- launch ----------------

extern "C" void kernel_launch(void* const* d_in, const int* in_sizes, int n_in,
                              void* d_out, int out_size, void* d_ws, size_t ws_size,
                              hipStream_t stream) {
    const float* x   = (const float*)d_in[0];
    const int*   ei  = (const int*)  d_in[1];
    const float* W1l = (const float*)d_in[2];
    const float* W1r = (const float*)d_in[3];
    const float* a1  = (const float*)d_in[4];
    const float* b1  = (const float*)d_in[5];
    const float* W2l = (const float*)d_in[6];
    const float* W2r = (const float*)d_in[7];
    const float* a2  = (const float*)d_in[8];
    const float* b2  = (const float*)d_in[9];
    float* out = (float*)d_out;

    char* ws = (char*)d_ws;
    size_t off = 0;
    auto carve = [&](size_t bytes) { char* p = ws + off; off += (bytes + 255) & ~size_t(255); return p; };
    int*   count     = (int*)  carve(N_NODES * sizeof(int));
    int*   row_start = (int*)  carve((N_NODES + 1) * sizeof(int));
    int*   cursor    = (int*)  carve(N_NODES * sizeof(int));
    int*   edge_src  = (int*)  carve(N_EDGE_T * sizeof(int));
    float* xl2       = (float*)carve(N_NODES * OUT_DIM * sizeof(float));
    float* xr2       = (float*)carve(N_NODES * OUT_DIM * sizeof(float));

    zero_kernel   <<<(N_NODES  + 255) / 256, 256, 0, stream>>>(count);
    count_kernel  <<<(N_EDGE_T + 255) / 256, 256, 0, stream>>>(ei, count);
    scan_kernel   <<<1, 1024, 0, stream>>>(count, row_start, cursor);
    scatter_kernel<<<(N_EDGE_T + 255) / 256, 256, 0, stream>>>(ei, cursor, edge_src);
    layer1_kernel <<<N_NODES / 4, 256, 0, stream>>>(x, W1l, W1r, a1, b1, W2l, W2r,
                                                    row_start, edge_src, xl2, xr2);
    layer2_kernel <<<(N_NODES + 3) / 4, 256, 0, stream>>>(xl2, xr2, a2, b2,
                                                          row_start, edge_src, out);
}